// Round 10
// baseline (1537.214 us; speedup 1.0000x reference)
//
#include <hip/hip_runtime.h>

typedef unsigned int uint;
typedef unsigned short ushort;
using short8 = __attribute__((ext_vector_type(8))) short;
using f32x4  = __attribute__((ext_vector_type(4))) float;

#define DEVFN __device__ __forceinline__

constexpr int B_ = 32, T_ = 128, E_ = 256, H_ = 512, A_ = 256, V_ = 32000, S_ = 64;
constexpr int G3_ = 3 * H_;          // 1536
constexpr int OUTIN_ = E_ + 4 * H_;  // 2304
constexpr int M_ = B_ * T_;          // 4096 rows, convention row = t*32 + b

DEVFN ushort f2b(float f) {  // f32 -> bf16 RNE
  uint u = __float_as_uint(f);
  u += 0x7fffu + ((u >> 16) & 1u);
  return (ushort)(u >> 16);
}
DEVFN float b2f(ushort b) { return __uint_as_float(((uint)b) << 16); }
DEVFN float sigmoid_f(float x) { return 1.f / (1.f + __expf(-x)); }
DEVFN float tanh_f(float x) { float e = __expf(2.f * x); return 1.f - 2.f / (e + 1.f); }

DEVFN void gload_lds16(const ushort* g, ushort* l) {  // async 16B global->LDS (m97 pattern)
  __builtin_amdgcn_global_load_lds(
      (const __attribute__((address_space(1))) void*)g,
      (__attribute__((address_space(3))) void*)l, 16, 0, 0);
}

// ---------------- transpose + convert: in f32 (R x C) -> out bf16 (C x R) ----------------
__global__ __launch_bounds__(256) void transpose_k(const float* __restrict__ in,
                                                   ushort* __restrict__ out, int R, int C) {
  __shared__ __align__(16) ushort tile[64][65];
  int c0 = blockIdx.x * 64, r0 = blockIdx.y * 64;
  int tx = threadIdx.x & 63, ty = threadIdx.x >> 6;
#pragma unroll
  for (int k = 0; k < 16; k++) {
    int i = ty + k * 4;
    int r = r0 + i, c = c0 + tx;
    if (r < R && c < C) tile[tx][i] = f2b(in[(size_t)r * C + c]);
  }
  __syncthreads();
#pragma unroll
  for (int k = 0; k < 16; k++) {
    int j = ty + k * 4;
    int c = c0 + j, r = r0 + tx;
    if (r < R && c < C) out[(size_t)c * R + r] = tile[j][tx];
  }
}

__global__ void convert_k(const float* __restrict__ in, ushort* __restrict__ out, int n) {
  int i = blockIdx.x * 256 + threadIdx.x;
  if (i < n) out[i] = f2b(in[i]);
}

// ---------------- embedding gather -> bf16, rows r = t*32+b ----------------
__global__ __launch_bounds__(256) void gather_k(const int* __restrict__ tokens,
                                                const float* __restrict__ emb,
                                                ushort* __restrict__ xbf) {
  int r = blockIdx.x;
  int t = r >> 5, b = r & 31;
  int tok = tokens[b * T_ + t];
  xbf[(size_t)r * E_ + threadIdx.x] = f2b(emb[(size_t)tok * E_ + threadIdx.x]);
}

// ---------------- kq[b][a] = knowledge[b] @ wq[E+H: E+2H] + bq ----------------
__global__ __launch_bounds__(256) void kq_k(const float* __restrict__ knowledge,
                                            const float* __restrict__ wq,
                                            const float* __restrict__ bq,
                                            float* __restrict__ kq) {
  int b = blockIdx.x, a = threadIdx.x;
  const float* kn = knowledge + b * H_;
  float s = 0.f;
  for (int h = 0; h < H_; h++) s += kn[h] * wq[(size_t)(E_ + H_ + h) * A_ + a];
  kq[b * A_ + a] = s + bq[a];
}

// ---------------- generic bf16 MFMA GEMM: C = A (MxK) * Bt^T (Bt is N x K) + bias ----------------
// OUTBF: 0 = f32 out, 1 = bf16 out (packed N stride), 2 = bf16 into f32-row slots (stride 2N)
// Staging via global_load_lds dwordx4 into unpadded linear LDS (m97 structure).
template <int OUTBF, int PERM, int HASBIAS>
__global__ __launch_bounds__(256) void gemm_bt(const ushort* __restrict__ Ag,
                                               const ushort* __restrict__ Btg,
                                               const float* __restrict__ bias,
                                               void* __restrict__ Cg, int M, int N, int K) {
  __shared__ __align__(16) ushort Ash[128 * 32];
  __shared__ __align__(16) ushort Bsh[128 * 32];
  // XCD-aware bijective swizzle (all grids here have nwg % 8 == 0)
  const int nbx = gridDim.x;
  const int nwg = nbx * gridDim.y;
  const int lin = blockIdx.y * nbx + blockIdx.x;
  const int cpx = nwg >> 3;
  const int swz = (lin & 7) * cpx + (lin >> 3);
  const int m0 = (swz / nbx) * 128, n0 = (swz % nbx) * 128;
  const int tid = threadIdx.x;
  const int wave = tid >> 6, lane = tid & 63, lr = lane & 15, lg = lane >> 4;
  const int wr = wave >> 1, wc = wave & 1;
  const int rb = lane >> 2, cb = (lane & 3) * 8;  // staging: row-in-block, col (ushorts)
  f32x4 acc[4][4] = {};
  for (int kk = 0; kk < K; kk += 32) {
#pragma unroll
    for (int j = 0; j < 2; j++) {
      int blk = wave * 2 + j;  // 0..7, 16 rows each
      gload_lds16(&Ag[(size_t)(m0 + blk * 16 + rb) * K + kk + cb], &Ash[blk * 16 * 32]);
      gload_lds16(&Btg[(size_t)(n0 + blk * 16 + rb) * K + kk + cb], &Bsh[blk * 16 * 32]);
    }
    __syncthreads();
    short8 af[4], bfr[4];
#pragma unroll
    for (int mi = 0; mi < 4; mi++)
      af[mi] = *(const short8*)&Ash[(wr * 64 + mi * 16 + lr) * 32 + lg * 8];
#pragma unroll
    for (int ni = 0; ni < 4; ni++)
      bfr[ni] = *(const short8*)&Bsh[(wc * 64 + ni * 16 + lr) * 32 + lg * 8];
#pragma unroll
    for (int mi = 0; mi < 4; mi++)
#pragma unroll
      for (int ni = 0; ni < 4; ni++)
        acc[mi][ni] = __builtin_amdgcn_mfma_f32_16x16x32_bf16(af[mi], bfr[ni], acc[mi][ni], 0, 0, 0);
    __syncthreads();
  }
#pragma unroll
  for (int mi = 0; mi < 4; mi++)
#pragma unroll
    for (int ni = 0; ni < 4; ni++) {
      int col = n0 + wc * 64 + ni * 16 + lr;
      float bv = HASBIAS ? bias[col] : 0.f;
#pragma unroll
      for (int r = 0; r < 4; r++) {
        int row = m0 + wr * 64 + mi * 16 + lg * 4 + r;
        int orow = PERM ? ((row & 31) << 7) + (row >> 5) : row;  // t*32+b -> b*128+t
        float v = acc[mi][ni][r] + bv;
        if (OUTBF == 1)      ((ushort*)Cg)[(size_t)orow * N + col] = f2b(v);
        else if (OUTBF == 2) ((ushort*)Cg)[(size_t)orow * 2 * N + col] = f2b(v);
        else                 ((float*)Cg)[(size_t)orow * N + col] = v;
      }
    }
}

// ---------------- init bf16 h slab 0 ----------------
__global__ void inith_k(const float* __restrict__ h0, ushort* __restrict__ hpb) {
  int g = blockIdx.x * 256 + threadIdx.x;  // < B_*H_
  hpb[g] = f2b(h0[g]);
}

// ---------------- persistent GRU scan: 32 WGs x 128 threads, WG owns 16 h-cols ----------------
// Round-6 proven sync, plus wave-split dependency: consumer wave w reads only slab rows
// 16w..16w+15, produced exclusively by wave w of each WG -> poll only those 32 flags.
__global__ __launch_bounds__(128, 1) void scan_k(
    const float* __restrict__ w_hh, const float* __restrict__ b_hh,
    const float* __restrict__ gi, const int* __restrict__ lengths,
    const float* __restrict__ h0, ushort* hpb,
    float* __restrict__ hidmem, float* __restrict__ hfinal, uint* flags) {
  __shared__ __align__(16) ushort pk[2][16][16];  // per-wave pack tile (intra-wave use only)
  const int wg = blockIdx.x;  // 0..31
  const int c0 = wg * 16;
  const int tid = threadIdx.x;
  const int wave = tid >> 6, lane = tid & 63, lr = lane & 15, lg = lane >> 4;
  const int c = c0 + lr;

  // preload bf16 weight fragments into registers (loop-invariant across all 128 steps)
  short8 wf0[16], wf1[16], wf2[16];
#pragma unroll
  for (int kk = 0; kk < 16; kk++) {
    short8 v0, v1, v2;
#pragma unroll
    for (int i = 0; i < 8; i++) {
      int k = kk * 32 + lg * 8 + i;
      v0[i] = (short)f2b(w_hh[(size_t)k * G3_ + 0 * H_ + c]);
      v1[i] = (short)f2b(w_hh[(size_t)k * G3_ + 1 * H_ + c]);
      v2[i] = (short)f2b(w_hh[(size_t)k * G3_ + 2 * H_ + c]);
    }
    wf0[kk] = v0; wf1[kk] = v1; wf2[kk] = v2;
  }
  const float bh0 = b_hh[c], bh1 = b_hh[H_ + c], bh2 = b_hh[2 * H_ + c];
  int len[4];
  float hp[4];
#pragma unroll
  for (int r = 0; r < 4; r++) {
    int bt = 16 * wave + lg * 4 + r;
    len[r] = lengths[bt];
    hp[r] = h0[(size_t)bt * H_ + c];
  }

  // wave w consumes rows produced by wave w of every WG -> flag slots (wg2*2 + wave)
  const uint fidx = ((uint)(lane & 31) * 2 + (uint)wave) * 32;

#pragma unroll 1
  for (int t = 0; t < T_; t++) {
    // prefetch gi for this step (independent of the barrier) — overlaps poll latency
    float g0[4], g1[4], g2[4];
#pragma unroll
    for (int r = 0; r < 4; r++) {
      int bt = 16 * wave + lg * 4 + r;
      const float* gr = gi + (size_t)(t * 32 + bt) * G3_ + c;
      g0[r] = gr[0]; g1[r] = gr[H_]; g2[r] = gr[2 * H_];
    }
    // wait only for this wave's 32 producers to publish slab t (slab 0 from inith_k)
    if (t > 0) {
      while (true) {
        uint f = __hip_atomic_load(&flags[fidx], __ATOMIC_RELAXED, __HIP_MEMORY_SCOPE_AGENT);
        if (__all((int)(f >= (uint)t))) break;
        __builtin_amdgcn_s_sleep(1);
      }
    }
    asm volatile("" ::: "memory");

    // A-fragments from slab t: plain dwordx4 loads (proven in r4/r6)
    const ushort* Sb = hpb + (size_t)t * (B_ * H_);
    const int rowA = 16 * wave + lr;
    f32x4 a0 = {}, a1 = {}, a2 = {};
#pragma unroll
    for (int kk = 0; kk < 16; kk++) {
      short8 av = *(const short8*)(Sb + rowA * H_ + kk * 32 + lg * 8);
      a0 = __builtin_amdgcn_mfma_f32_16x16x32_bf16(av, wf0[kk], a0, 0, 0, 0);
      a1 = __builtin_amdgcn_mfma_f32_16x16x32_bf16(av, wf1[kk], a1, 0, 0, 0);
      a2 = __builtin_amdgcn_mfma_f32_16x16x32_bf16(av, wf2[kk], a2, 0, 0, 0);
    }

    // elementwise GRU update; stage bf16(hx) into the per-wave LDS pack tile
    ushort* Un16 = hpb + (size_t)(t + 1) * (B_ * H_);
    float hmv[4];
#pragma unroll
    for (int r = 0; r < 4; r++) {
      float rr = sigmoid_f(g0[r] + a0[r] + bh0);
      float zz = sigmoid_f(g1[r] + a1[r] + bh1);
      float nn = tanh_f(g2[r] + rr * (a2[r] + bh2));
      float hv = (1.f - zz) * nn + zz * hp[r];
      bool valid = t < len[r];
      float hx = valid ? hv : hp[r];
      hp[r] = hx;
      hmv[r] = valid ? hv : 0.f;
      pk[wave][lg * 4 + r][lr] = f2b(hx);
    }
    // pack: 16 rows x 32B per wave -> 32 dwordx4 sc1 stores
    if (lane < 32) {
      int row = lane >> 1, half = lane & 1;
      short8 v = *(const short8*)&pk[wave][row][half * 8];
      ushort* gp = Un16 + ((size_t)(16 * wave + row) * H_ + c0 + half * 8);
      asm volatile("global_store_dwordx4 %0, %1, off sc1" :: "v"(gp), "v"(v) : "memory");
    }
    // drain ONLY the publish stores, then relaxed per-wave flag (padded slot)
    asm volatile("s_waitcnt vmcnt(0)" ::: "memory");
    if (lane == 0)
      __hip_atomic_store(&flags[(wg * 2 + wave) * 32], (uint)(t + 1),
                         __ATOMIC_RELAXED, __HIP_MEMORY_SCOPE_AGENT);
    // hidmem stores off the critical path
#pragma unroll
    for (int r = 0; r < 4; r++) {
      int bt = 16 * wave + lg * 4 + r;
      hidmem[((size_t)bt * T_ + t) * H_ + c] = hmv[r];
    }
  }
#pragma unroll
  for (int r = 0; r < 4; r++) {
    int bt = 16 * wave + lg * 4 + r;
    hfinal[(size_t)bt * H_ + c] = hp[r];
  }
}

// ---------------- MLP attention (scores + softmax + context), one block per (b,t) ----------------
__global__ __launch_bounds__(256) void attn_k(
    const float* __restrict__ qxk, const float* __restrict__ qh, const float* __restrict__ kq,
    const float* __restrict__ mk, const float* __restrict__ mem, const float* __restrict__ vvec,
    const int* __restrict__ slen, float* __restrict__ ctx) {
  __shared__ float qf[A_], vv[A_], sc[S_];
  int bx = blockIdx.x;  // b*T + t (b-major for mem L2 locality)
  int b = bx >> 7, t = bx & 127;
  int row = t * B_ + b;
  int tid = threadIdx.x;
  qf[tid] = qxk[(size_t)row * A_ + tid] + qh[(size_t)row * A_ + tid] + kq[b * A_ + tid];
  vv[tid] = vvec[tid];
  __syncthreads();
  int s = tid >> 2, q4 = tid & 3;
  const float* mkr = mk + ((size_t)(b * S_) + s) * A_;
  float part = 0.f;
#pragma unroll 4
  for (int i = 0; i < 64; i++) {
    int a = q4 + (i << 2);  // quad-interleaved -> coalesced 16B per quad
    part += tanh_f(qf[a] + mkr[a]) * vv[a];
  }
  part += __shfl_xor(part, 1, 64);
  part += __shfl_xor(part, 2, 64);
  if (q4 == 0) sc[s] = part;
  __syncthreads();
  if (tid < S_) {
    float v = (tid < slen[b]) ? sc[tid] : -1e9f;
    float mm = v;
    for (int off = 1; off < 64; off <<= 1) mm = fmaxf(mm, __shfl_xor(mm, off, 64));
    float e = __expf(v - mm);
    float ss = e;
    for (int off = 1; off < 64; off <<= 1) ss += __shfl_xor(ss, off, 64);
    sc[tid] = e / ss;
  }
  __syncthreads();
  float c0 = 0.f, c1 = 0.f;
  const float* mb = mem + (size_t)b * S_ * H_;
  for (int ss2 = 0; ss2 < S_; ss2++) {
    float w = sc[ss2];
    c0 += w * mb[ss2 * H_ + tid];
    c1 += w * mb[ss2 * H_ + tid + 256];
  }
  ctx[(size_t)row * H_ + tid] = c0;
  ctx[(size_t)row * H_ + tid + 256] = c1;
}

// ---------------- assemble out_in (bf16, masked); h_new taken from hidmem ----------------
__global__ __launch_bounds__(256) void assemble_k(
    const ushort* __restrict__ xbf, const float* __restrict__ hm,
    const float* __restrict__ knowledge, const float* __restrict__ ctxs,
    const float* __restrict__ ctxc, const int* __restrict__ lengths,
    ushort* __restrict__ outin) {
  int r = blockIdx.x;
  int t = r >> 5, b = r & 31;
  bool valid = t < lengths[b];
  int tid = threadIdx.x;
  ushort* dst = outin + (size_t)r * OUTIN_;
#pragma unroll
  for (int kblk = 0; kblk < 9; kblk++) {
    int i = kblk * 256 + tid;
    ushort v;
    if (i < E_)               v = xbf[(size_t)r * E_ + i];
    else if (i < E_ + H_)     v = f2b(hm[((size_t)b * T_ + t) * H_ + i - E_]);
    else if (i < E_ + 2 * H_) v = f2b(knowledge[b * H_ + i - (E_ + H_)]);
    else if (i < E_ + 3 * H_) v = f2b(ctxs[(size_t)r * H_ + i - (E_ + 2 * H_)]);
    else                      v = f2b(ctxc[(size_t)r * H_ + i - (E_ + 3 * H_)]);
    dst[i] = valid ? v : (ushort)0;
  }
}

// ---------------- row log_softmax: bf16 logits (first half of f32 row slot) -> f32 out ----------------
// Chunks held in statically-indexed registers (no LDS, no global re-read).
__global__ __launch_bounds__(256) void logsoftmax_k(float* __restrict__ logits) {
  __shared__ float redm[4], reds[4];
  float* row = logits + (size_t)blockIdx.x * V_;
  const short8* rg = (const short8*)row;  // bf16 payload occupies first V_*2 bytes
  const int tid = threadIdx.x;
  short8 buf[16];
  float m = -3.4e38f, s = 0.f;
#pragma unroll
  for (int k = 0; k < 16; k++) {
    int i = tid + k * 256;
    if (i < V_ / 8) {
      short8 v = rg[i];
      buf[k] = v;
      float f0 = b2f((ushort)v[0]), f1 = b2f((ushort)v[1]);
      float f2 = b2f((ushort)v[2]), f3 = b2f((ushort)v[3]);
      float f4 = b2f((ushort)v[4]), f5 = b2f((ushort)v[5]);
      float f6 = b2f((ushort)v[6]), f7 = b2f((ushort)v[7]);
      float vm = fmaxf(fmaxf(fmaxf(f0, f1), fmaxf(f2, f3)),
                       fmaxf(fmaxf(f4, f5), fmaxf(f6, f7)));
      float nm = fmaxf(m, vm);
      s = s * __expf(m - nm) + __expf(f0 - nm) + __expf(f1 - nm) + __expf(f2 - nm) +
          __expf(f3 - nm) + __expf(f4 - nm) + __expf(f5 - nm) + __expf(f6 - nm) +
          __expf(f7 - nm);
      m = nm;
    }
  }
  for (int off = 1; off < 64; off <<= 1) {
    float om = __shfl_xor(m, off, 64), os = __shfl_xor(s, off, 64);
    float nm = fmaxf(m, om);
    s = s * __expf(m - nm) + os * __expf(om - nm);
    m = nm;
  }
  if ((tid & 63) == 0) { redm[tid >> 6] = m; reds[tid >> 6] = s; }
  __syncthreads();
  float M = fmaxf(fmaxf(redm[0], redm[1]), fmaxf(redm[2], redm[3]));
  float S = reds[0] * __expf(redm[0] - M) + reds[1] * __expf(redm[1] - M) +
            reds[2] * __expf(redm[2] - M) + reds[3] * __expf(redm[3] - M);
  float lse = M + __logf(S);
  __syncthreads();  // all reads of bf16 payload complete before f32 overwrite
#pragma unroll
  for (int k = 0; k < 16; k++) {
    int i = tid + k * 256;
    if (i < V_ / 8) {
      short8 v = buf[k];
      float4 o0, o1;
      o0.x = b2f((ushort)v[0]) - lse; o0.y = b2f((ushort)v[1]) - lse;
      o0.z = b2f((ushort)v[2]) - lse; o0.w = b2f((ushort)v[3]) - lse;
      o1.x = b2f((ushort)v[4]) - lse; o1.y = b2f((ushort)v[5]) - lse;
      o1.z = b2f((ushort)v[6]) - lse; o1.w = b2f((ushort)v[7]) - lse;
      *(float4*)&row[i * 8] = o0;
      *(float4*)&row[i * 8 + 4] = o1;
    }
  }
}

extern "C" void kernel_launch(void* const* d_in, const int* in_sizes, int n_in,
                              void* d_out, int out_size, void* d_ws, size_t ws_size,
                              hipStream_t stream) {
  const int*   tokens    = (const int*)  d_in[0];
  const int*   lengths   = (const int*)  d_in[1];
  const float* hidden0   = (const float*)d_in[2];
  const float* knowledge = (const float*)d_in[3];
  const float* src_mem   = (const float*)d_in[4];
  const int*   src_len   = (const int*)  d_in[5];
  const float* cue_mem   = (const float*)d_in[6];
  const int*   cue_len   = (const int*)  d_in[7];
  const float* emb       = (const float*)d_in[8];
  const float* w_ih      = (const float*)d_in[9];
  const float* w_hh      = (const float*)d_in[10];
  const float* b_ih      = (const float*)d_in[11];
  const float* b_hh      = (const float*)d_in[12];
  const float* src_wq    = (const float*)d_in[13];
  const float* src_bq    = (const float*)d_in[14];
  const float* src_wm    = (const float*)d_in[15];
  const float* src_v     = (const float*)d_in[16];
  const float* cue_wq    = (const float*)d_in[17];
  const float* cue_bq    = (const float*)d_in[18];
  const float* cue_wm    = (const float*)d_in[19];
  const float* cue_v     = (const float*)d_in[20];
  const float* w_out1    = (const float*)d_in[21];
  const float* b_out1    = (const float*)d_in[22];
  const float* w_out2    = (const float*)d_in[23];
  const float* b_out2    = (const float*)d_in[24];

  float* out_lp = (float*)d_out;                    // (B,T,V)
  float* out_hm = out_lp + (size_t)M_ * V_;         // (B,T,H)
  float* out_hf = out_hm + (size_t)M_ * H_;         // (B,H)

  // ---- scratch carved out of the (not-yet-written) logits region of d_out ----
  char* scb = (char*)d_out;
  size_t off = 0;
  auto alloc = [&](size_t bytes) -> void* {
    void* p = scb + off;
    off = (off + bytes + 255) & ~(size_t)255;
    return p;
  };
  float*  GI    = (float*) alloc((size_t)M_ * G3_ * 4);
  float*  QXKs  = (float*) alloc((size_t)M_ * A_ * 4);
  float*  QXKc  = (float*) alloc((size_t)M_ * A_ * 4);
  float*  QHs   = (float*) alloc((size_t)M_ * A_ * 4);
  float*  QHc   = (float*) alloc((size_t)M_ * A_ * 4);
  float*  CTXs  = (float*) alloc((size_t)M_ * H_ * 4);
  float*  CTXc  = (float*) alloc((size_t)M_ * H_ * 4);
  ushort* OUTIN = (ushort*)alloc((size_t)M_ * OUTIN_ * 2);
  ushort* XBF   = (ushort*)alloc((size_t)M_ * E_ * 2);
  ushort* WIHT  = (ushort*)alloc((size_t)G3_ * E_ * 2);
  ushort* WQXTs = (ushort*)alloc((size_t)A_ * E_ * 2);
  ushort* WQXTc = (ushort*)alloc((size_t)A_ * E_ * 2);
  ushort* WQHTs = (ushort*)alloc((size_t)A_ * H_ * 2);
  ushort* WQHTc = (ushort*)alloc((size_t)A_ * H_ * 2);
  ushort* WMTs  = (ushort*)alloc((size_t)A_ * H_ * 2);
  ushort* WMTc  = (ushort*)alloc((size_t)A_ * H_ * 2);
  ushort* WO1T  = (ushort*)alloc((size_t)H_ * OUTIN_ * 2);
  ushort* MEMBs = (ushort*)alloc((size_t)B_ * S_ * H_ * 2);
  ushort* MEMBc = (ushort*)alloc((size_t)B_ * S_ * H_ * 2);
  float*  MKs   = (float*) alloc((size_t)B_ * S_ * A_ * 4);
  float*  MKc   = (float*) alloc((size_t)B_ * S_ * A_ * 4);
  float*  KQs   = (float*) alloc((size_t)B_ * A_ * 4);
  float*  KQc   = (float*) alloc((size_t)B_ * A_ * 4);
  ushort* HPB   = (ushort*)alloc((size_t)(T_ + 1) * B_ * H_ * 2);  // bf16 h slabs

  // ---- d_ws: padded barrier flags + what must survive into the logits GEMM ----
  uint* FLAGS = (uint*)d_ws;                                          // 64 x 128B slots
  ushort* WO2T = (ushort*)((char*)d_ws + 8192);                       // (V x H) bf16
  ushort* HID1 = (ushort*)((char*)d_ws + 8192 + (size_t)V_ * H_ * 2); // (M x H) bf16

  dim3 blk(256);
  hipMemsetAsync(FLAGS, 0, 8192, stream);

  // weight transposes (f32 KxN -> bf16 NxK)
  transpose_k<<<dim3(G3_ / 64, E_ / 64), blk, 0, stream>>>(w_ih, WIHT, E_, G3_);
  transpose_k<<<dim3(A_ / 64, E_ / 64), blk, 0, stream>>>(src_wq, WQXTs, E_, A_);
  transpose_k<<<dim3(A_ / 64, H_ / 64), blk, 0, stream>>>(src_wq + (size_t)E_ * A_, WQHTs, H_, A_);
  transpose_k<<<dim3(A_ / 64, E_ / 64), blk, 0, stream>>>(cue_wq, WQXTc, E_, A_);
  transpose_k<<<dim3(A_ / 64, H_ / 64), blk, 0, stream>>>(cue_wq + (size_t)E_ * A_, WQHTc, H_, A_);
  transpose_k<<<dim3(A_ / 64, H_ / 64), blk, 0, stream>>>(src_wm, WMTs, H_, A_);
  transpose_k<<<dim3(A_ / 64, H_ / 64), blk, 0, stream>>>(cue_wm, WMTc, H_, A_);
  transpose_k<<<dim3(H_ / 64, OUTIN_ / 64), blk, 0, stream>>>(w_out1, WO1T, OUTIN_, H_);
  transpose_k<<<dim3(V_ / 64, H_ / 64), blk, 0, stream>>>(w_out2, WO2T, H_, V_);
  convert_k<<<(B_ * S_ * H_ + 255) / 256, blk, 0, stream>>>(src_mem, MEMBs, B_ * S_ * H_);
  convert_k<<<(B_ * S_ * H_ + 255) / 256, blk, 0, stream>>>(cue_mem, MEMBc, B_ * S_ * H_);

  gather_k<<<M_, blk, 0, stream>>>(tokens, emb, XBF);
  kq_k<<<B_, blk, 0, stream>>>(knowledge, src_wq, src_bq, KQs);
  kq_k<<<B_, blk, 0, stream>>>(knowledge, cue_wq, cue_bq, KQc);

  // precompute GEMMs
  gemm_bt<0, 0, 1><<<dim3(G3_ / 128, M_ / 128), blk, 0, stream>>>(XBF, WIHT, b_ih, GI, M_, G3_, E_);
  gemm_bt<0, 0, 0><<<dim3(A_ / 128, M_ / 128), blk, 0, stream>>>(XBF, WQXTs, nullptr, QXKs, M_, A_, E_);
  gemm_bt<0, 0, 0><<<dim3(A_ / 128, M_ / 128), blk, 0, stream>>>(XBF, WQXTc, nullptr, QXKc, M_, A_, E_);
  gemm_bt<0, 0, 0><<<dim3(A_ / 128, (B_ * S_) / 128), blk, 0, stream>>>(MEMBs, WMTs, nullptr, MKs, B_ * S_, A_, H_);
  gemm_bt<0, 0, 0><<<dim3(A_ / 128, (B_ * S_) / 128), blk, 0, stream>>>(MEMBc, WMTc, nullptr, MKc, B_ * S_, A_, H_);

  // sequential GRU scan (32 persistent WGs, reg-resident weights, wave-split flag barrier)
  inith_k<<<(B_ * H_) / 256, blk, 0, stream>>>(hidden0, HPB);
  scan_k<<<32, dim3(128), 0, stream>>>(w_hh, b_hh, GI, lengths, hidden0, HPB, out_hm, out_hf, FLAGS);

  // parallel attention over all (b,t)
  gemm_bt<0, 0, 0><<<dim3(A_ / 128, M_ / 128), blk, 0, stream>>>(HPB, WQHTs, nullptr, QHs, M_, A_, H_);
  gemm_bt<0, 0, 0><<<dim3(A_ / 128, M_ / 128), blk, 0, stream>>>(HPB, WQHTc, nullptr, QHc, M_, A_, H_);
  attn_k<<<M_, blk, 0, stream>>>(QXKs, QHs, KQs, MKs, src_mem, src_v, src_len, CTXs);
  attn_k<<<M_, blk, 0, stream>>>(QXKc, QHc, KQc, MKc, cue_mem, cue_v, cue_len, CTXc);

  // output head: logits as bf16 into the f32 row slots, then fused LSE+subtract
  assemble_k<<<M_, blk, 0, stream>>>(XBF, out_hm, knowledge, CTXs, CTXc, lengths, OUTIN);
  gemm_bt<1, 0, 1><<<dim3(H_ / 128, M_ / 128), blk, 0, stream>>>(OUTIN, WO1T, b_out1, HID1, M_, H_, OUTIN_);
  gemm_bt<2, 1, 1><<<dim3(V_ / 128, M_ / 128), blk, 0, stream>>>(HID1, WO2T, b_out2, out_lp, M_, V_, H_);
  logsoftmax_k<<<M_, blk, 0, stream>>>(out_lp);
}

// Round 13
// 1494.564 us; speedup vs baseline: 1.0285x; 1.0285x over previous
//
#include <hip/hip_runtime.h>

typedef unsigned int uint;
typedef unsigned short ushort;
using short8 = __attribute__((ext_vector_type(8))) short;
using f32x4  = __attribute__((ext_vector_type(4))) float;

#define DEVFN __device__ __forceinline__

constexpr int B_ = 32, T_ = 128, E_ = 256, H_ = 512, A_ = 256, V_ = 32000, S_ = 64;
constexpr int G3_ = 3 * H_;          // 1536
constexpr int OUTIN_ = E_ + 4 * H_;  // 2304
constexpr int M_ = B_ * T_;          // 4096 rows, convention row = t*32 + b

DEVFN ushort f2b(float f) {  // f32 -> bf16 RNE
  uint u = __float_as_uint(f);
  u += 0x7fffu + ((u >> 16) & 1u);
  return (ushort)(u >> 16);
}
DEVFN float b2f(ushort b) { return __uint_as_float(((uint)b) << 16); }
DEVFN float sigmoid_f(float x) { return 1.f / (1.f + __expf(-x)); }
DEVFN float tanh_f(float x) { float e = __expf(2.f * x); return 1.f - 2.f / (e + 1.f); }

// ---------------- transpose + convert: in f32 (R x C) -> out bf16 (C x R) ----------------
__global__ __launch_bounds__(256) void transpose_k(const float* __restrict__ in,
                                                   ushort* __restrict__ out, int R, int C) {
  __shared__ __align__(16) ushort tile[64][65];
  int c0 = blockIdx.x * 64, r0 = blockIdx.y * 64;
  int tx = threadIdx.x & 63, ty = threadIdx.x >> 6;
#pragma unroll
  for (int k = 0; k < 16; k++) {
    int i = ty + k * 4;
    int r = r0 + i, c = c0 + tx;
    if (r < R && c < C) tile[tx][i] = f2b(in[(size_t)r * C + c]);
  }
  __syncthreads();
#pragma unroll
  for (int k = 0; k < 16; k++) {
    int j = ty + k * 4;
    int c = c0 + j, r = r0 + tx;
    if (r < R && c < C) out[(size_t)c * R + r] = tile[j][tx];
  }
}

__global__ void convert_k(const float* __restrict__ in, ushort* __restrict__ out, int n) {
  int i = blockIdx.x * 256 + threadIdx.x;
  if (i < n) out[i] = f2b(in[i]);
}

// ---------------- embedding gather -> bf16, rows r = t*32+b ----------------
__global__ __launch_bounds__(256) void gather_k(const int* __restrict__ tokens,
                                                const float* __restrict__ emb,
                                                ushort* __restrict__ xbf) {
  int r = blockIdx.x;
  int t = r >> 5, b = r & 31;
  int tok = tokens[b * T_ + t];
  xbf[(size_t)r * E_ + threadIdx.x] = f2b(emb[(size_t)tok * E_ + threadIdx.x]);
}

// ---------------- kq[b][a] = knowledge[b] @ wq[E+H: E+2H] + bq ----------------
__global__ __launch_bounds__(256) void kq_k(const float* __restrict__ knowledge,
                                            const float* __restrict__ wq,
                                            const float* __restrict__ bq,
                                            float* __restrict__ kq) {
  int b = blockIdx.x, a = threadIdx.x;
  const float* kn = knowledge + b * H_;
  float s = 0.f;
  for (int h = 0; h < H_; h++) s += kn[h] * wq[(size_t)(E_ + H_ + h) * A_ + a];
  kq[b * A_ + a] = s + bq[a];
}

// ---------------- generic bf16 MFMA GEMM (r9-proven staging + XCD swizzle) ----------------
// OUTBF: 0 = f32 out, 1 = bf16 out (packed N stride), 2 = bf16 into f32-row slots (stride 2N)
template <int OUTBF, int PERM, int HASBIAS>
__global__ __launch_bounds__(256) void gemm_bt(const ushort* __restrict__ Ag,
                                               const ushort* __restrict__ Btg,
                                               const float* __restrict__ bias,
                                               void* __restrict__ Cg, int M, int N, int K) {
  __shared__ __align__(16) ushort Ash[128][40];
  __shared__ __align__(16) ushort Bsh[128][40];
  const int nbx = gridDim.x;
  const int nwg = nbx * gridDim.y;
  const int lin = blockIdx.y * nbx + blockIdx.x;
  const int cpx = nwg >> 3;
  const int swz = (lin & 7) * cpx + (lin >> 3);
  const int m0 = (swz / nbx) * 128, n0 = (swz % nbx) * 128;
  const int tid = threadIdx.x;
  const int wave = tid >> 6, lane = tid & 63, lr = lane & 15, lg = lane >> 4;
  const int wr = wave >> 1, wc = wave & 1;
  f32x4 acc[4][4] = {};
  for (int kk = 0; kk < K; kk += 32) {
    {
      int r = tid >> 2, q = tid & 3;
      *(short8*)&Ash[r][q * 8] = *(const short8*)&Ag[(size_t)(m0 + r) * K + kk + q * 8];
      *(short8*)&Bsh[r][q * 8] = *(const short8*)&Btg[(size_t)(n0 + r) * K + kk + q * 8];
      r += 64;
      *(short8*)&Ash[r][q * 8] = *(const short8*)&Ag[(size_t)(m0 + r) * K + kk + q * 8];
      *(short8*)&Bsh[r][q * 8] = *(const short8*)&Btg[(size_t)(n0 + r) * K + kk + q * 8];
    }
    __syncthreads();
    short8 af[4], bfr[4];
#pragma unroll
    for (int mi = 0; mi < 4; mi++) af[mi] = *(const short8*)&Ash[wr * 64 + mi * 16 + lr][lg * 8];
#pragma unroll
    for (int ni = 0; ni < 4; ni++) bfr[ni] = *(const short8*)&Bsh[wc * 64 + ni * 16 + lr][lg * 8];
#pragma unroll
    for (int mi = 0; mi < 4; mi++)
#pragma unroll
      for (int ni = 0; ni < 4; ni++)
        acc[mi][ni] = __builtin_amdgcn_mfma_f32_16x16x32_bf16(af[mi], bfr[ni], acc[mi][ni], 0, 0, 0);
    __syncthreads();
  }
#pragma unroll
  for (int mi = 0; mi < 4; mi++)
#pragma unroll
    for (int ni = 0; ni < 4; ni++) {
      int col = n0 + wc * 64 + ni * 16 + lr;
      float bv = HASBIAS ? bias[col] : 0.f;
#pragma unroll
      for (int r = 0; r < 4; r++) {
        int row = m0 + wr * 64 + mi * 16 + lg * 4 + r;
        int orow = PERM ? ((row & 31) << 7) + (row >> 5) : row;  // t*32+b -> b*128+t
        float v = acc[mi][ni][r] + bv;
        if (OUTBF == 1)      ((ushort*)Cg)[(size_t)orow * N + col] = f2b(v);
        else if (OUTBF == 2) ((ushort*)Cg)[(size_t)orow * 2 * N + col] = f2b(v);
        else                 ((float*)Cg)[(size_t)orow * N + col] = v;
      }
    }
}

// ---------------- init bf16 h slab 0 ----------------
__global__ void inith_k(const float* __restrict__ h0, ushort* __restrict__ hpb) {
  int g = blockIdx.x * 256 + threadIdx.x;  // < B_*H_
  hpb[g] = f2b(h0[g]);
}

// ---------------- persistent GRU scan: 32 WGs x 128 threads, WG owns 16 h-cols ----------------
// r6-proven sync + r10-proven wave-split dependency: consumer wave w reads only slab rows
// 16w..16w+15, produced exclusively by wave w of each WG -> poll only those 32 flags.
__global__ __launch_bounds__(128, 1) void scan_k(
    const float* __restrict__ w_hh, const float* __restrict__ b_hh,
    const float* __restrict__ gi, const int* __restrict__ lengths,
    const float* __restrict__ h0, ushort* hpb,
    float* __restrict__ hidmem, float* __restrict__ hfinal, uint* flags) {
  __shared__ __align__(16) ushort pk[2][16][16];  // per-wave pack tile (intra-wave use only)
  const int wg = blockIdx.x;  // 0..31
  const int c0 = wg * 16;
  const int tid = threadIdx.x;
  const int wave = tid >> 6, lane = tid & 63, lr = lane & 15, lg = lane >> 4;
  const int c = c0 + lr;

  // preload bf16 weight fragments into registers (loop-invariant across all 128 steps)
  short8 wf0[16], wf1[16], wf2[16];
#pragma unroll
  for (int kk = 0; kk < 16; kk++) {
    short8 v0, v1, v2;
#pragma unroll
    for (int i = 0; i < 8; i++) {
      int k = kk * 32 + lg * 8 + i;
      v0[i] = (short)f2b(w_hh[(size_t)k * G3_ + 0 * H_ + c]);
      v1[i] = (short)f2b(w_hh[(size_t)k * G3_ + 1 * H_ + c]);
      v2[i] = (short)f2b(w_hh[(size_t)k * G3_ + 2 * H_ + c]);
    }
    wf0[kk] = v0; wf1[kk] = v1; wf2[kk] = v2;
  }
  const float bh0 = b_hh[c], bh1 = b_hh[H_ + c], bh2 = b_hh[2 * H_ + c];
  int len[4];
  float hp[4];
#pragma unroll
  for (int r = 0; r < 4; r++) {
    int bt = 16 * wave + lg * 4 + r;
    len[r] = lengths[bt];
    hp[r] = h0[(size_t)bt * H_ + c];
  }

  // wave w consumes rows produced by wave w of every WG -> flag slots (wg2*2 + wave)
  const uint fidx = ((uint)(lane & 31) * 2 + (uint)wave) * 32;

#pragma unroll 1
  for (int t = 0; t < T_; t++) {
    // prefetch gi for this step (independent of the barrier) — overlaps poll latency
    float g0[4], g1[4], g2[4];
#pragma unroll
    for (int r = 0; r < 4; r++) {
      int bt = 16 * wave + lg * 4 + r;
      const float* gr = gi + (size_t)(t * 32 + bt) * G3_ + c;
      g0[r] = gr[0]; g1[r] = gr[H_]; g2[r] = gr[2 * H_];
    }
    // wait only for this wave's 32 producers to publish slab t (slab 0 from inith_k)
    if (t > 0) {
      while (true) {
        uint f = __hip_atomic_load(&flags[fidx], __ATOMIC_RELAXED, __HIP_MEMORY_SCOPE_AGENT);
        if (__all((int)(f >= (uint)t))) break;
        __builtin_amdgcn_s_sleep(1);
      }
    }
    asm volatile("" ::: "memory");

    // A-fragments from slab t: plain dwordx4 loads (proven in r4/r6)
    const ushort* Sb = hpb + (size_t)t * (B_ * H_);
    const int rowA = 16 * wave + lr;
    f32x4 a0 = {}, a1 = {}, a2 = {};
#pragma unroll
    for (int kk = 0; kk < 16; kk++) {
      short8 av = *(const short8*)(Sb + rowA * H_ + kk * 32 + lg * 8);
      a0 = __builtin_amdgcn_mfma_f32_16x16x32_bf16(av, wf0[kk], a0, 0, 0, 0);
      a1 = __builtin_amdgcn_mfma_f32_16x16x32_bf16(av, wf1[kk], a1, 0, 0, 0);
      a2 = __builtin_amdgcn_mfma_f32_16x16x32_bf16(av, wf2[kk], a2, 0, 0, 0);
    }

    // elementwise GRU update; stage bf16(hx) into the per-wave LDS pack tile
    ushort* Un16 = hpb + (size_t)(t + 1) * (B_ * H_);
    float hmv[4];
#pragma unroll
    for (int r = 0; r < 4; r++) {
      float rr = sigmoid_f(g0[r] + a0[r] + bh0);
      float zz = sigmoid_f(g1[r] + a1[r] + bh1);
      float nn = tanh_f(g2[r] + rr * (a2[r] + bh2));
      float hv = (1.f - zz) * nn + zz * hp[r];
      bool valid = t < len[r];
      float hx = valid ? hv : hp[r];
      hp[r] = hx;
      hmv[r] = valid ? hv : 0.f;
      pk[wave][lg * 4 + r][lr] = f2b(hx);
    }
    // pack: 16 rows x 32B per wave -> 32 dwordx4 sc1 stores
    if (lane < 32) {
      int row = lane >> 1, half = lane & 1;
      short8 v = *(const short8*)&pk[wave][row][half * 8];
      ushort* gp = Un16 + ((size_t)(16 * wave + row) * H_ + c0 + half * 8);
      asm volatile("global_store_dwordx4 %0, %1, off sc1" :: "v"(gp), "v"(v) : "memory");
    }
    // drain ONLY the publish stores, then relaxed per-wave flag (padded slot)
    asm volatile("s_waitcnt vmcnt(0)" ::: "memory");
    if (lane == 0)
      __hip_atomic_store(&flags[(wg * 2 + wave) * 32], (uint)(t + 1),
                         __ATOMIC_RELAXED, __HIP_MEMORY_SCOPE_AGENT);
    // hidmem stores off the critical path
#pragma unroll
    for (int r = 0; r < 4; r++) {
      int bt = 16 * wave + lg * 4 + r;
      hidmem[((size_t)bt * T_ + t) * H_ + c] = hmv[r];
    }
  }
#pragma unroll
  for (int r = 0; r < 4; r++) {
    int bt = 16 * wave + lg * 4 + r;
    hfinal[(size_t)bt * H_ + c] = hp[r];
  }
}

// ---------------- MLP attention (scores + softmax + context), one block per (b,t) ----------------
__global__ __launch_bounds__(256) void attn_k(
    const float* __restrict__ qxk, const float* __restrict__ qh, const float* __restrict__ kq,
    const float* __restrict__ mk, const float* __restrict__ mem, const float* __restrict__ vvec,
    const int* __restrict__ slen, float* __restrict__ ctx) {
  __shared__ float qf[A_], vv[A_], sc[S_];
  int bx = blockIdx.x;  // b*T + t (b-major for mem L2 locality)
  int b = bx >> 7, t = bx & 127;
  int row = t * B_ + b;
  int tid = threadIdx.x;
  qf[tid] = qxk[(size_t)row * A_ + tid] + qh[(size_t)row * A_ + tid] + kq[b * A_ + tid];
  vv[tid] = vvec[tid];
  __syncthreads();
  int s = tid >> 2, q4 = tid & 3;
  const float* mkr = mk + ((size_t)(b * S_) + s) * A_;
  float part = 0.f;
#pragma unroll 4
  for (int i = 0; i < 64; i++) {
    int a = q4 + (i << 2);  // quad-interleaved -> coalesced 16B per quad
    part += tanh_f(qf[a] + mkr[a]) * vv[a];
  }
  part += __shfl_xor(part, 1, 64);
  part += __shfl_xor(part, 2, 64);
  if (q4 == 0) sc[s] = part;
  __syncthreads();
  if (tid < S_) {
    float v = (tid < slen[b]) ? sc[tid] : -1e9f;
    float mm = v;
    for (int off = 1; off < 64; off <<= 1) mm = fmaxf(mm, __shfl_xor(mm, off, 64));
    float e = __expf(v - mm);
    float ss = e;
    for (int off = 1; off < 64; off <<= 1) ss += __shfl_xor(ss, off, 64);
    sc[tid] = e / ss;
  }
  __syncthreads();
  float c0 = 0.f, c1 = 0.f;
  const float* mb = mem + (size_t)b * S_ * H_;
  for (int ss2 = 0; ss2 < S_; ss2++) {
    float w = sc[ss2];
    c0 += w * mb[ss2 * H_ + tid];
    c1 += w * mb[ss2 * H_ + tid + 256];
  }
  ctx[(size_t)row * H_ + tid] = c0;
  ctx[(size_t)row * H_ + tid + 256] = c1;
}

// ---------------- assemble out_in (bf16, masked); h_new taken from hidmem ----------------
__global__ __launch_bounds__(256) void assemble_k(
    const ushort* __restrict__ xbf, const float* __restrict__ hm,
    const float* __restrict__ knowledge, const float* __restrict__ ctxs,
    const float* __restrict__ ctxc, const int* __restrict__ lengths,
    ushort* __restrict__ outin) {
  int r = blockIdx.x;
  int t = r >> 5, b = r & 31;
  bool valid = t < lengths[b];
  int tid = threadIdx.x;
  ushort* dst = outin + (size_t)r * OUTIN_;
#pragma unroll
  for (int kblk = 0; kblk < 9; kblk++) {
    int i = kblk * 256 + tid;
    ushort v;
    if (i < E_)               v = xbf[(size_t)r * E_ + i];
    else if (i < E_ + H_)     v = f2b(hm[((size_t)b * T_ + t) * H_ + i - E_]);
    else if (i < E_ + 2 * H_) v = f2b(knowledge[b * H_ + i - (E_ + H_)]);
    else if (i < E_ + 3 * H_) v = f2b(ctxs[(size_t)r * H_ + i - (E_ + 2 * H_)]);
    else                      v = f2b(ctxc[(size_t)r * H_ + i - (E_ + 3 * H_)]);
    dst[i] = valid ? v : (ushort)0;
  }
}

// ---------------- row log_softmax: bf16 logits (first half of f32 row slot) -> f32 out ----------------
// Chunks held in statically-indexed registers (no LDS, no global re-read).
__global__ __launch_bounds__(256) void logsoftmax_k(float* __restrict__ logits) {
  __shared__ float redm[4], reds[4];
  float* row = logits + (size_t)blockIdx.x * V_;
  const short8* rg = (const short8*)row;  // bf16 payload occupies first V_*2 bytes
  const int tid = threadIdx.x;
  short8 buf[16];
  float m = -3.4e38f, s = 0.f;
#pragma unroll
  for (int k = 0; k < 16; k++) {
    int i = tid + k * 256;
    if (i < V_ / 8) {
      short8 v = rg[i];
      buf[k] = v;
      float f0 = b2f((ushort)v[0]), f1 = b2f((ushort)v[1]);
      float f2 = b2f((ushort)v[2]), f3 = b2f((ushort)v[3]);
      float f4 = b2f((ushort)v[4]), f5 = b2f((ushort)v[5]);
      float f6 = b2f((ushort)v[6]), f7 = b2f((ushort)v[7]);
      float vm = fmaxf(fmaxf(fmaxf(f0, f1), fmaxf(f2, f3)),
                       fmaxf(fmaxf(f4, f5), fmaxf(f6, f7)));
      float nm = fmaxf(m, vm);
      s = s * __expf(m - nm) + __expf(f0 - nm) + __expf(f1 - nm) + __expf(f2 - nm) +
          __expf(f3 - nm) + __expf(f4 - nm) + __expf(f5 - nm) + __expf(f6 - nm) +
          __expf(f7 - nm);
      m = nm;
    }
  }
  for (int off = 1; off < 64; off <<= 1) {
    float om = __shfl_xor(m, off, 64), os = __shfl_xor(s, off, 64);
    float nm = fmaxf(m, om);
    s = s * __expf(m - nm) + os * __expf(om - nm);
    m = nm;
  }
  if ((tid & 63) == 0) { redm[tid >> 6] = m; reds[tid >> 6] = s; }
  __syncthreads();
  float M = fmaxf(fmaxf(redm[0], redm[1]), fmaxf(redm[2], redm[3]));
  float S = reds[0] * __expf(redm[0] - M) + reds[1] * __expf(redm[1] - M) +
            reds[2] * __expf(redm[2] - M) + reds[3] * __expf(redm[3] - M);
  float lse = M + __logf(S);
  __syncthreads();  // all reads of bf16 payload complete before f32 overwrite
#pragma unroll
  for (int k = 0; k < 16; k++) {
    int i = tid + k * 256;
    if (i < V_ / 8) {
      short8 v = buf[k];
      float4 o0, o1;
      o0.x = b2f((ushort)v[0]) - lse; o0.y = b2f((ushort)v[1]) - lse;
      o0.z = b2f((ushort)v[2]) - lse; o0.w = b2f((ushort)v[3]) - lse;
      o1.x = b2f((ushort)v[4]) - lse; o1.y = b2f((ushort)v[5]) - lse;
      o1.z = b2f((ushort)v[6]) - lse; o1.w = b2f((ushort)v[7]) - lse;
      *(float4*)&row[i * 8] = o0;
      *(float4*)&row[i * 8 + 4] = o1;
    }
  }
}

extern "C" void kernel_launch(void* const* d_in, const int* in_sizes, int n_in,
                              void* d_out, int out_size, void* d_ws, size_t ws_size,
                              hipStream_t stream) {
  const int*   tokens    = (const int*)  d_in[0];
  const int*   lengths   = (const int*)  d_in[1];
  const float* hidden0   = (const float*)d_in[2];
  const float* knowledge = (const float*)d_in[3];
  const float* src_mem   = (const float*)d_in[4];
  const int*   src_len   = (const int*)  d_in[5];
  const float* cue_mem   = (const float*)d_in[6];
  const int*   cue_len   = (const int*)  d_in[7];
  const float* emb       = (const float*)d_in[8];
  const float* w_ih      = (const float*)d_in[9];
  const float* w_hh      = (const float*)d_in[10];
  const float* b_ih      = (const float*)d_in[11];
  const float* b_hh      = (const float*)d_in[12];
  const float* src_wq    = (const float*)d_in[13];
  const float* src_bq    = (const float*)d_in[14];
  const float* src_wm    = (const float*)d_in[15];
  const float* src_v     = (const float*)d_in[16];
  const float* cue_wq    = (const float*)d_in[17];
  const float* cue_bq    = (const float*)d_in[18];
  const float* cue_wm    = (const float*)d_in[19];
  const float* cue_v     = (const float*)d_in[20];
  const float* w_out1    = (const float*)d_in[21];
  const float* b_out1    = (const float*)d_in[22];
  const float* w_out2    = (const float*)d_in[23];
  const float* b_out2    = (const float*)d_in[24];

  float* out_lp = (float*)d_out;                    // (B,T,V)
  float* out_hm = out_lp + (size_t)M_ * V_;         // (B,T,H)
  float* out_hf = out_hm + (size_t)M_ * H_;         // (B,H)

  // ---- scratch carved out of the (not-yet-written) logits region of d_out ----
  char* scb = (char*)d_out;
  size_t off = 0;
  auto alloc = [&](size_t bytes) -> void* {
    void* p = scb + off;
    off = (off + bytes + 255) & ~(size_t)255;
    return p;
  };
  float*  GI    = (float*) alloc((size_t)M_ * G3_ * 4);
  float*  QXKs  = (float*) alloc((size_t)M_ * A_ * 4);
  float*  QXKc  = (float*) alloc((size_t)M_ * A_ * 4);
  float*  QHs   = (float*) alloc((size_t)M_ * A_ * 4);
  float*  QHc   = (float*) alloc((size_t)M_ * A_ * 4);
  float*  CTXs  = (float*) alloc((size_t)M_ * H_ * 4);
  float*  CTXc  = (float*) alloc((size_t)M_ * H_ * 4);
  ushort* OUTIN = (ushort*)alloc((size_t)M_ * OUTIN_ * 2);
  ushort* XBF   = (ushort*)alloc((size_t)M_ * E_ * 2);
  ushort* WIHT  = (ushort*)alloc((size_t)G3_ * E_ * 2);
  ushort* WQXTs = (ushort*)alloc((size_t)A_ * E_ * 2);
  ushort* WQXTc = (ushort*)alloc((size_t)A_ * E_ * 2);
  ushort* WQHTs = (ushort*)alloc((size_t)A_ * H_ * 2);
  ushort* WQHTc = (ushort*)alloc((size_t)A_ * H_ * 2);
  ushort* WMTs  = (ushort*)alloc((size_t)A_ * H_ * 2);
  ushort* WMTc  = (ushort*)alloc((size_t)A_ * H_ * 2);
  ushort* WO1T  = (ushort*)alloc((size_t)H_ * OUTIN_ * 2);
  ushort* MEMBs = (ushort*)alloc((size_t)B_ * S_ * H_ * 2);
  ushort* MEMBc = (ushort*)alloc((size_t)B_ * S_ * H_ * 2);
  float*  MKs   = (float*) alloc((size_t)B_ * S_ * A_ * 4);
  float*  MKc   = (float*) alloc((size_t)B_ * S_ * A_ * 4);
  float*  KQs   = (float*) alloc((size_t)B_ * A_ * 4);
  float*  KQc   = (float*) alloc((size_t)B_ * A_ * 4);
  ushort* HPB   = (ushort*)alloc((size_t)(T_ + 1) * B_ * H_ * 2);  // bf16 h slabs

  // ---- d_ws: padded barrier flags + what must survive into the logits GEMM ----
  uint* FLAGS = (uint*)d_ws;                                          // 64 x 128B slots
  ushort* WO2T = (ushort*)((char*)d_ws + 8192);                       // (V x H) bf16
  ushort* HID1 = (ushort*)((char*)d_ws + 8192 + (size_t)V_ * H_ * 2); // (M x H) bf16

  dim3 blk(256);
  hipMemsetAsync(FLAGS, 0, 8192, stream);

  // weight transposes (f32 KxN -> bf16 NxK)
  transpose_k<<<dim3(G3_ / 64, E_ / 64), blk, 0, stream>>>(w_ih, WIHT, E_, G3_);
  transpose_k<<<dim3(A_ / 64, E_ / 64), blk, 0, stream>>>(src_wq, WQXTs, E_, A_);
  transpose_k<<<dim3(A_ / 64, H_ / 64), blk, 0, stream>>>(src_wq + (size_t)E_ * A_, WQHTs, H_, A_);
  transpose_k<<<dim3(A_ / 64, E_ / 64), blk, 0, stream>>>(cue_wq, WQXTc, E_, A_);
  transpose_k<<<dim3(A_ / 64, H_ / 64), blk, 0, stream>>>(cue_wq + (size_t)E_ * A_, WQHTc, H_, A_);
  transpose_k<<<dim3(A_ / 64, H_ / 64), blk, 0, stream>>>(src_wm, WMTs, H_, A_);
  transpose_k<<<dim3(A_ / 64, H_ / 64), blk, 0, stream>>>(cue_wm, WMTc, H_, A_);
  transpose_k<<<dim3(H_ / 64, OUTIN_ / 64), blk, 0, stream>>>(w_out1, WO1T, OUTIN_, H_);
  transpose_k<<<dim3(V_ / 64, H_ / 64), blk, 0, stream>>>(w_out2, WO2T, H_, V_);
  convert_k<<<(B_ * S_ * H_ + 255) / 256, blk, 0, stream>>>(src_mem, MEMBs, B_ * S_ * H_);
  convert_k<<<(B_ * S_ * H_ + 255) / 256, blk, 0, stream>>>(cue_mem, MEMBc, B_ * S_ * H_);

  gather_k<<<M_, blk, 0, stream>>>(tokens, emb, XBF);
  kq_k<<<B_, blk, 0, stream>>>(knowledge, src_wq, src_bq, KQs);
  kq_k<<<B_, blk, 0, stream>>>(knowledge, cue_wq, cue_bq, KQc);

  // precompute GEMMs
  gemm_bt<0, 0, 1><<<dim3(G3_ / 128, M_ / 128), blk, 0, stream>>>(XBF, WIHT, b_ih, GI, M_, G3_, E_);
  gemm_bt<0, 0, 0><<<dim3(A_ / 128, M_ / 128), blk, 0, stream>>>(XBF, WQXTs, nullptr, QXKs, M_, A_, E_);
  gemm_bt<0, 0, 0><<<dim3(A_ / 128, M_ / 128), blk, 0, stream>>>(XBF, WQXTc, nullptr, QXKc, M_, A_, E_);
  gemm_bt<0, 0, 0><<<dim3(A_ / 128, (B_ * S_) / 128), blk, 0, stream>>>(MEMBs, WMTs, nullptr, MKs, B_ * S_, A_, H_);
  gemm_bt<0, 0, 0><<<dim3(A_ / 128, (B_ * S_) / 128), blk, 0, stream>>>(MEMBc, WMTc, nullptr, MKc, B_ * S_, A_, H_);

  // sequential GRU scan (32 persistent WGs, reg-resident weights, wave-split flag barrier)
  inith_k<<<(B_ * H_) / 256, blk, 0, stream>>>(hidden0, HPB);
  scan_k<<<32, dim3(128), 0, stream>>>(w_hh, b_hh, GI, lengths, hidden0, HPB, out_hm, out_hf, FLAGS);

  // parallel attention over all (b,t)
  gemm_bt<0, 0, 0><<<dim3(A_ / 128, M_ / 128), blk, 0, stream>>>(HPB, WQHTs, nullptr, QHs, M_, A_, H_);
  gemm_bt<0, 0, 0><<<dim3(A_ / 128, M_ / 128), blk, 0, stream>>>(HPB, WQHTc, nullptr, QHc, M_, A_, H_);
  attn_k<<<M_, blk, 0, stream>>>(QXKs, QHs, KQs, MKs, src_mem, src_v, src_len, CTXs);
  attn_k<<<M_, blk, 0, stream>>>(QXKc, QHc, KQc, MKc, cue_mem, cue_v, cue_len, CTXc);

  // output head: logits as bf16 into the f32 row slots, then fused LSE+subtract
  assemble_k<<<M_, blk, 0, stream>>>(XBF, out_hm, knowledge, CTXs, CTXc, lengths, OUTIN);
  gemm_bt<1, 0, 1><<<dim3(H_ / 128, M_ / 128), blk, 0, stream>>>(OUTIN, WO1T, b_out1, HID1, M_, H_, OUTIN_);
  gemm_bt<2, 1, 1><<<dim3(V_ / 128, M_ / 128), blk, 0, stream>>>(HID1, WO2T, b_out2, out_lp, M_, V_, H_);
  logsoftmax_k<<<M_, blk, 0, stream>>>(out_lp);
}

// Round 14
// 1400.056 us; speedup vs baseline: 1.0980x; 1.0675x over previous
//
#include <hip/hip_runtime.h>

typedef unsigned int uint;
typedef unsigned short ushort;
using short8 = __attribute__((ext_vector_type(8))) short;
using f32x4  = __attribute__((ext_vector_type(4))) float;

#define DEVFN __device__ __forceinline__

constexpr int B_ = 32, T_ = 128, E_ = 256, H_ = 512, A_ = 256, V_ = 32000, S_ = 64;
constexpr int G3_ = 3 * H_;          // 1536
constexpr int OUTIN_ = E_ + 4 * H_;  // 2304
constexpr int M_ = B_ * T_;          // 4096 rows, convention row = t*32 + b

DEVFN ushort f2b(float f) {  // f32 -> bf16 RNE
  uint u = __float_as_uint(f);
  u += 0x7fffu + ((u >> 16) & 1u);
  return (ushort)(u >> 16);
}
DEVFN float b2f(ushort b) { return __uint_as_float(((uint)b) << 16); }
DEVFN float sigmoid_f(float x) { return 1.f / (1.f + __expf(-x)); }
DEVFN float tanh_f(float x) { float e = __expf(2.f * x); return 1.f - 2.f / (e + 1.f); }
DEVFN f32x4 MFMA16(short8 a, short8 b, f32x4 c) {
  return __builtin_amdgcn_mfma_f32_16x16x32_bf16(a, b, c, 0, 0, 0);
}

// ---------------- transpose + convert: in f32 (R x C) -> out bf16 (C x R) ----------------
__global__ __launch_bounds__(256) void transpose_k(const float* __restrict__ in,
                                                   ushort* __restrict__ out, int R, int C) {
  __shared__ __align__(16) ushort tile[64][65];
  int c0 = blockIdx.x * 64, r0 = blockIdx.y * 64;
  int tx = threadIdx.x & 63, ty = threadIdx.x >> 6;
#pragma unroll
  for (int k = 0; k < 16; k++) {
    int i = ty + k * 4;
    int r = r0 + i, c = c0 + tx;
    if (r < R && c < C) tile[tx][i] = f2b(in[(size_t)r * C + c]);
  }
  __syncthreads();
#pragma unroll
  for (int k = 0; k < 16; k++) {
    int j = ty + k * 4;
    int c = c0 + j, r = r0 + tx;
    if (r < R && c < C) out[(size_t)c * R + r] = tile[j][tx];
  }
}

__global__ void convert_k(const float* __restrict__ in, ushort* __restrict__ out, int n) {
  int i = blockIdx.x * 256 + threadIdx.x;
  if (i < n) out[i] = f2b(in[i]);
}

// ---------------- embedding gather -> bf16, rows r = t*32+b ----------------
__global__ __launch_bounds__(256) void gather_k(const int* __restrict__ tokens,
                                                const float* __restrict__ emb,
                                                ushort* __restrict__ xbf) {
  int r = blockIdx.x;
  int t = r >> 5, b = r & 31;
  int tok = tokens[b * T_ + t];
  xbf[(size_t)r * E_ + threadIdx.x] = f2b(emb[(size_t)tok * E_ + threadIdx.x]);
}

// ---------------- generic bf16 MFMA GEMM (r9-proven staging + XCD swizzle) ----------------
// OUTBF: 0 = f32 out, 1 = bf16 out (packed N stride), 2 = bf16 into f32-row slots (stride 2N)
template <int OUTBF, int PERM, int HASBIAS>
__global__ __launch_bounds__(256) void gemm_bt(const ushort* __restrict__ Ag,
                                               const ushort* __restrict__ Btg,
                                               const float* __restrict__ bias,
                                               void* __restrict__ Cg, int M, int N, int K) {
  __shared__ __align__(16) ushort Ash[128][40];
  __shared__ __align__(16) ushort Bsh[128][40];
  const int nbx = gridDim.x;
  const int nwg = nbx * gridDim.y;
  const int lin = blockIdx.y * nbx + blockIdx.x;
  const int cpx = nwg >> 3;
  const int swz = (lin & 7) * cpx + (lin >> 3);
  const int m0 = (swz / nbx) * 128, n0 = (swz % nbx) * 128;
  const int tid = threadIdx.x;
  const int wave = tid >> 6, lane = tid & 63, lr = lane & 15, lg = lane >> 4;
  const int wr = wave >> 1, wc = wave & 1;
  f32x4 acc[4][4] = {};
  for (int kk = 0; kk < K; kk += 32) {
    {
      int r = tid >> 2, q = tid & 3;
      *(short8*)&Ash[r][q * 8] = *(const short8*)&Ag[(size_t)(m0 + r) * K + kk + q * 8];
      *(short8*)&Bsh[r][q * 8] = *(const short8*)&Btg[(size_t)(n0 + r) * K + kk + q * 8];
      r += 64;
      *(short8*)&Ash[r][q * 8] = *(const short8*)&Ag[(size_t)(m0 + r) * K + kk + q * 8];
      *(short8*)&Bsh[r][q * 8] = *(const short8*)&Btg[(size_t)(n0 + r) * K + kk + q * 8];
    }
    __syncthreads();
    short8 af[4], bfr[4];
#pragma unroll
    for (int mi = 0; mi < 4; mi++) af[mi] = *(const short8*)&Ash[wr * 64 + mi * 16 + lr][lg * 8];
#pragma unroll
    for (int ni = 0; ni < 4; ni++) bfr[ni] = *(const short8*)&Bsh[wc * 64 + ni * 16 + lr][lg * 8];
#pragma unroll
    for (int mi = 0; mi < 4; mi++)
#pragma unroll
      for (int ni = 0; ni < 4; ni++)
        acc[mi][ni] = MFMA16(af[mi], bfr[ni], acc[mi][ni]);
    __syncthreads();
  }
#pragma unroll
  for (int mi = 0; mi < 4; mi++)
#pragma unroll
    for (int ni = 0; ni < 4; ni++) {
      int col = n0 + wc * 64 + ni * 16 + lr;
      float bv = HASBIAS ? bias[col] : 0.f;
#pragma unroll
      for (int r = 0; r < 4; r++) {
        int row = m0 + wr * 64 + mi * 16 + lg * 4 + r;
        int orow = PERM ? ((row & 31) << 7) + (row >> 5) : row;  // t*32+b -> b*128+t
        float v = acc[mi][ni][r] + bv;
        if (OUTBF == 1)      ((ushort*)Cg)[(size_t)orow * N + col] = f2b(v);
        else if (OUTBF == 2) ((ushort*)Cg)[(size_t)orow * 2 * N + col] = f2b(v);
        else                 ((float*)Cg)[(size_t)orow * N + col] = v;
      }
    }
}

// ---------------- init bf16 h slab 0 ----------------
__global__ void inith_k(const float* __restrict__ h0, ushort* __restrict__ hpb) {
  int g = blockIdx.x * 256 + threadIdx.x;  // < B_*H_
  hpb[g] = f2b(h0[g]);
}

// ================= fused scan + independent-prologue-work kernel =================
// bid 0..31: r13-proven scan (tid<128; no __syncthreads in that path).
// bid 32..255: static grid-stride over 4544 jobs with ZERO dependencies on the scan
// or on each other (all inputs were produced by earlier kernels in-stream).
struct FArgs {
  // scan
  const float *w_hh, *b_hh, *gi, *h0;
  const int* lengths;
  ushort* hpb;
  float *hidmem, *hfinal;
  uint* flags;
  // workers
  const float *w_out1, *w_out2, *knowledge, *src_wq, *src_bq, *cue_wq, *cue_bq;
  ushort *wo1t, *wo2t;
  float *kqs, *kqc;
  const ushort *xbf, *wqxts, *wqxtc, *membs, *membc, *wmts, *wmtc;
  float *qxks, *qxkc, *mks, *mkc;
};

DEVFN void scan_body(const FArgs& P, int wg, int tid, char* smem) {
  ushort (*pk)[16][16] = (ushort(*)[16][16])smem;
  const int c0 = wg * 16;
  const int wave = tid >> 6, lane = tid & 63, lr = lane & 15, lg = lane >> 4;
  const int c = c0 + lr;

  short8 wf0[16], wf1[16], wf2[16];
#pragma unroll
  for (int kk = 0; kk < 16; kk++) {
    short8 v0, v1, v2;
#pragma unroll
    for (int i = 0; i < 8; i++) {
      int k = kk * 32 + lg * 8 + i;
      v0[i] = (short)f2b(P.w_hh[(size_t)k * G3_ + 0 * H_ + c]);
      v1[i] = (short)f2b(P.w_hh[(size_t)k * G3_ + 1 * H_ + c]);
      v2[i] = (short)f2b(P.w_hh[(size_t)k * G3_ + 2 * H_ + c]);
    }
    wf0[kk] = v0; wf1[kk] = v1; wf2[kk] = v2;
  }
  const float bh0 = P.b_hh[c], bh1 = P.b_hh[H_ + c], bh2 = P.b_hh[2 * H_ + c];
  int len[4];
  float hp[4];
#pragma unroll
  for (int r = 0; r < 4; r++) {
    int bt = 16 * wave + lg * 4 + r;
    len[r] = P.lengths[bt];
    hp[r] = P.h0[(size_t)bt * H_ + c];
  }
  const uint fidx = ((uint)(lane & 31) * 2 + (uint)wave) * 32;

#pragma unroll 1
  for (int t = 0; t < T_; t++) {
    float g0[4], g1[4], g2[4];
#pragma unroll
    for (int r = 0; r < 4; r++) {
      int bt = 16 * wave + lg * 4 + r;
      const float* gr = P.gi + (size_t)(t * 32 + bt) * G3_ + c;
      g0[r] = gr[0]; g1[r] = gr[H_]; g2[r] = gr[2 * H_];
    }
    if (t > 0) {
      while (true) {
        uint f = __hip_atomic_load(&P.flags[fidx], __ATOMIC_RELAXED, __HIP_MEMORY_SCOPE_AGENT);
        if (__all((int)(f >= (uint)t))) break;
        __builtin_amdgcn_s_sleep(1);
      }
    }
    asm volatile("" ::: "memory");

    const ushort* Sb = P.hpb + (size_t)t * (B_ * H_);
    const int rowA = 16 * wave + lr;
    f32x4 a0 = {}, a1 = {}, a2 = {};
#pragma unroll
    for (int kk = 0; kk < 16; kk++) {
      short8 av = *(const short8*)(Sb + rowA * H_ + kk * 32 + lg * 8);
      a0 = MFMA16(av, wf0[kk], a0);
      a1 = MFMA16(av, wf1[kk], a1);
      a2 = MFMA16(av, wf2[kk], a2);
    }

    ushort* Un16 = P.hpb + (size_t)(t + 1) * (B_ * H_);
    float hmv[4];
#pragma unroll
    for (int r = 0; r < 4; r++) {
      float rr = sigmoid_f(g0[r] + a0[r] + bh0);
      float zz = sigmoid_f(g1[r] + a1[r] + bh1);
      float nn = tanh_f(g2[r] + rr * (a2[r] + bh2));
      float hv = (1.f - zz) * nn + zz * hp[r];
      bool valid = t < len[r];
      float hx = valid ? hv : hp[r];
      hp[r] = hx;
      hmv[r] = valid ? hv : 0.f;
      pk[wave][lg * 4 + r][lr] = f2b(hx);
    }
    if (lane < 32) {
      int row = lane >> 1, half = lane & 1;
      short8 v = *(const short8*)&pk[wave][row][half * 8];
      ushort* gp = Un16 + ((size_t)(16 * wave + row) * H_ + c0 + half * 8);
      asm volatile("global_store_dwordx4 %0, %1, off sc1" :: "v"(gp), "v"(v) : "memory");
    }
    asm volatile("s_waitcnt vmcnt(0)" ::: "memory");
    if (lane == 0)
      __hip_atomic_store(&P.flags[(wg * 2 + wave) * 32], (uint)(t + 1),
                         __ATOMIC_RELAXED, __HIP_MEMORY_SCOPE_AGENT);
#pragma unroll
    for (int r = 0; r < 4; r++) {
      int bt = 16 * wave + lg * 4 + r;
      P.hidmem[((size_t)bt * T_ + t) * H_ + c] = hmv[r];
    }
  }
#pragma unroll
  for (int r = 0; r < 4; r++) {
    int bt = 16 * wave + lg * 4 + r;
    P.hfinal[(size_t)bt * H_ + c] = hp[r];
  }
}

// ---- worker job bodies (no inter-job dependencies) ----
DEVFN void trans_tile(const float* in, ushort* out, int R, int C, int bx, int by,
                      int tid, char* smem) {
  ushort (*tile)[65] = (ushort(*)[65])smem;
  int c0 = bx * 64, r0 = by * 64;
  int tx = tid & 63, ty = tid >> 6;
#pragma unroll
  for (int k = 0; k < 16; k++) {
    int i = ty + k * 4;
    int r = r0 + i, c = c0 + tx;
    if (r < R && c < C) tile[tx][i] = f2b(in[(size_t)r * C + c]);
  }
  __syncthreads();
#pragma unroll
  for (int k = 0; k < 16; k++) {
    int j = ty + k * 4;
    int c = c0 + j, r = r0 + tx;
    if (r < R && c < C) out[(size_t)c * R + r] = tile[j][tx];
  }
  __syncthreads();  // smem reused by next job
}

DEVFN void kq_job(const float* knowledge, const float* wq, const float* bq,
                  float* kq, int b, int tid) {
  const float* kn = knowledge + b * H_;
  float s = 0.f;
  for (int h = 0; h < H_; h++) s += kn[h] * wq[(size_t)(E_ + H_ + h) * A_ + tid];
  kq[b * A_ + tid] = s + bq[tid];
}

DEVFN void gemm_tile(const ushort* Ag, const ushort* Btg, float* Cg,
                     int N, int K, int m0, int n0, int tid, char* smem) {
  ushort (*Ash)[40] = (ushort(*)[40])smem;
  ushort (*Bsh)[40] = (ushort(*)[40])(smem + 10240);
  const int wave = tid >> 6, lane = tid & 63, lr = lane & 15, lg = lane >> 4;
  const int wr = wave >> 1, wc = wave & 1;
  f32x4 acc[4][4] = {};
  for (int kk = 0; kk < K; kk += 32) {
    {
      int r = tid >> 2, q = tid & 3;
      *(short8*)&Ash[r][q * 8] = *(const short8*)&Ag[(size_t)(m0 + r) * K + kk + q * 8];
      *(short8*)&Bsh[r][q * 8] = *(const short8*)&Btg[(size_t)(n0 + r) * K + kk + q * 8];
      r += 64;
      *(short8*)&Ash[r][q * 8] = *(const short8*)&Ag[(size_t)(m0 + r) * K + kk + q * 8];
      *(short8*)&Bsh[r][q * 8] = *(const short8*)&Btg[(size_t)(n0 + r) * K + kk + q * 8];
    }
    __syncthreads();
    short8 af[4], bfr[4];
#pragma unroll
    for (int mi = 0; mi < 4; mi++) af[mi] = *(const short8*)&Ash[wr * 64 + mi * 16 + lr][lg * 8];
#pragma unroll
    for (int ni = 0; ni < 4; ni++) bfr[ni] = *(const short8*)&Bsh[wc * 64 + ni * 16 + lr][lg * 8];
#pragma unroll
    for (int mi = 0; mi < 4; mi++)
#pragma unroll
      for (int ni = 0; ni < 4; ni++)
        acc[mi][ni] = MFMA16(af[mi], bfr[ni], acc[mi][ni]);
    __syncthreads();
  }
#pragma unroll
  for (int mi = 0; mi < 4; mi++)
#pragma unroll
    for (int ni = 0; ni < 4; ni++) {
      int col = n0 + wc * 64 + ni * 16 + lr;
#pragma unroll
      for (int r = 0; r < 4; r++) {
        int row = m0 + wr * 64 + mi * 16 + lg * 4 + r;
        Cg[(size_t)row * N + col] = acc[mi][ni][r];
      }
    }
}

constexpr int NJOB = 288 + 4000 + 64 + 128 + 64;  // 4544

__global__ __launch_bounds__(256, 1) void scanfused_k(FArgs P) {
  __shared__ __align__(16) char smem[20480];
  const int bid = blockIdx.x, tid = threadIdx.x;
  if (bid < 32) {
    if (tid < 128) scan_body(P, bid, tid, smem);
    return;
  }
  for (int j = bid - 32; j < NJOB; j += 224) {
    if (j < 288) {
      trans_tile(P.w_out1, P.wo1t, OUTIN_, H_, j & 7, j >> 3, tid, smem);
    } else if (j < 4288) {
      int q = j - 288;
      trans_tile(P.w_out2, P.wo2t, H_, V_, q % 500, q / 500, tid, smem);
    } else if (j < 4352) {
      int q = j - 4288;
      if (q < 32) kq_job(P.knowledge, P.src_wq, P.src_bq, P.kqs, q, tid);
      else        kq_job(P.knowledge, P.cue_wq, P.cue_bq, P.kqc, q - 32, tid);
    } else if (j < 4480) {
      int q = j - 4352;
      int mat = q >> 6; q &= 63;
      gemm_tile(P.xbf, mat ? P.wqxtc : P.wqxts, mat ? P.qxkc : P.qxks,
                A_, E_, (q >> 1) * 128, (q & 1) * 128, tid, smem);
    } else {
      int q = j - 4480;
      int mat = q >> 5; q &= 31;
      gemm_tile(mat ? P.membc : P.membs, mat ? P.wmtc : P.wmts, mat ? P.mkc : P.mks,
                A_, H_, (q >> 1) * 128, (q & 1) * 128, tid, smem);
    }
  }
}

// ---------------- MLP attention (bf16 mem reads), one block per (b,t) ----------------
__global__ __launch_bounds__(256) void attn_k(
    const float* __restrict__ qxk, const float* __restrict__ qh, const float* __restrict__ kq,
    const float* __restrict__ mk, const ushort* __restrict__ memb, const float* __restrict__ vvec,
    const int* __restrict__ slen, float* __restrict__ ctx) {
  __shared__ float qf[A_], vv[A_], sc[S_];
  int bx = blockIdx.x;  // b*T + t (b-major for mem L2 locality)
  int b = bx >> 7, t = bx & 127;
  int row = t * B_ + b;
  int tid = threadIdx.x;
  qf[tid] = qxk[(size_t)row * A_ + tid] + qh[(size_t)row * A_ + tid] + kq[b * A_ + tid];
  vv[tid] = vvec[tid];
  __syncthreads();
  int s = tid >> 2, q4 = tid & 3;
  const float* mkr = mk + ((size_t)(b * S_) + s) * A_;
  float part = 0.f;
#pragma unroll 4
  for (int i = 0; i < 64; i++) {
    int a = q4 + (i << 2);  // quad-interleaved -> coalesced 16B per quad
    part += tanh_f(qf[a] + mkr[a]) * vv[a];
  }
  part += __shfl_xor(part, 1, 64);
  part += __shfl_xor(part, 2, 64);
  if (q4 == 0) sc[s] = part;
  __syncthreads();
  if (tid < S_) {
    float v = (tid < slen[b]) ? sc[tid] : -1e9f;
    float mm = v;
    for (int off = 1; off < 64; off <<= 1) mm = fmaxf(mm, __shfl_xor(mm, off, 64));
    float e = __expf(v - mm);
    float ss = e;
    for (int off = 1; off < 64; off <<= 1) ss += __shfl_xor(ss, off, 64);
    sc[tid] = e / ss;
  }
  __syncthreads();
  float c0 = 0.f, c1 = 0.f;
  const ushort* mb = memb + (size_t)b * S_ * H_;
  for (int ss2 = 0; ss2 < S_; ss2++) {
    float w = sc[ss2];
    c0 += w * b2f(mb[ss2 * H_ + tid]);
    c1 += w * b2f(mb[ss2 * H_ + tid + 256]);
  }
  ctx[(size_t)row * H_ + tid] = c0;
  ctx[(size_t)row * H_ + tid + 256] = c1;
}

// ---------------- assemble out_in (bf16, masked); h_new taken from hidmem ----------------
__global__ __launch_bounds__(256) void assemble_k(
    const ushort* __restrict__ xbf, const float* __restrict__ hm,
    const float* __restrict__ knowledge, const float* __restrict__ ctxs,
    const float* __restrict__ ctxc, const int* __restrict__ lengths,
    ushort* __restrict__ outin) {
  int r = blockIdx.x;
  int t = r >> 5, b = r & 31;
  bool valid = t < lengths[b];
  int tid = threadIdx.x;
  ushort* dst = outin + (size_t)r * OUTIN_;
#pragma unroll
  for (int kblk = 0; kblk < 9; kblk++) {
    int i = kblk * 256 + tid;
    ushort v;
    if (i < E_)               v = xbf[(size_t)r * E_ + i];
    else if (i < E_ + H_)     v = f2b(hm[((size_t)b * T_ + t) * H_ + i - E_]);
    else if (i < E_ + 2 * H_) v = f2b(knowledge[b * H_ + i - (E_ + H_)]);
    else if (i < E_ + 3 * H_) v = f2b(ctxs[(size_t)r * H_ + i - (E_ + 2 * H_)]);
    else                      v = f2b(ctxc[(size_t)r * H_ + i - (E_ + 3 * H_)]);
    dst[i] = valid ? v : (ushort)0;
  }
}

// ---------------- row log_softmax: bf16 logits (first half of f32 row slot) -> f32 out ----------------
__global__ __launch_bounds__(256) void logsoftmax_k(float* __restrict__ logits) {
  __shared__ float redm[4], reds[4];
  float* row = logits + (size_t)blockIdx.x * V_;
  const short8* rg = (const short8*)row;  // bf16 payload occupies first V_*2 bytes
  const int tid = threadIdx.x;
  short8 buf[16];
  float m = -3.4e38f, s = 0.f;
#pragma unroll
  for (int k = 0; k < 16; k++) {
    int i = tid + k * 256;
    if (i < V_ / 8) {
      short8 v = rg[i];
      buf[k] = v;
      float f0 = b2f((ushort)v[0]), f1 = b2f((ushort)v[1]);
      float f2 = b2f((ushort)v[2]), f3 = b2f((ushort)v[3]);
      float f4 = b2f((ushort)v[4]), f5 = b2f((ushort)v[5]);
      float f6 = b2f((ushort)v[6]), f7 = b2f((ushort)v[7]);
      float vm = fmaxf(fmaxf(fmaxf(f0, f1), fmaxf(f2, f3)),
                       fmaxf(fmaxf(f4, f5), fmaxf(f6, f7)));
      float nm = fmaxf(m, vm);
      s = s * __expf(m - nm) + __expf(f0 - nm) + __expf(f1 - nm) + __expf(f2 - nm) +
          __expf(f3 - nm) + __expf(f4 - nm) + __expf(f5 - nm) + __expf(f6 - nm) +
          __expf(f7 - nm);
      m = nm;
    }
  }
  for (int off = 1; off < 64; off <<= 1) {
    float om = __shfl_xor(m, off, 64), os = __shfl_xor(s, off, 64);
    float nm = fmaxf(m, om);
    s = s * __expf(m - nm) + os * __expf(om - nm);
    m = nm;
  }
  if ((tid & 63) == 0) { redm[tid >> 6] = m; reds[tid >> 6] = s; }
  __syncthreads();
  float M = fmaxf(fmaxf(redm[0], redm[1]), fmaxf(redm[2], redm[3]));
  float S = reds[0] * __expf(redm[0] - M) + reds[1] * __expf(redm[1] - M) +
            reds[2] * __expf(redm[2] - M) + reds[3] * __expf(redm[3] - M);
  float lse = M + __logf(S);
  __syncthreads();  // all reads of bf16 payload complete before f32 overwrite
#pragma unroll
  for (int k = 0; k < 16; k++) {
    int i = tid + k * 256;
    if (i < V_ / 8) {
      short8 v = buf[k];
      float4 o0, o1;
      o0.x = b2f((ushort)v[0]) - lse; o0.y = b2f((ushort)v[1]) - lse;
      o0.z = b2f((ushort)v[2]) - lse; o0.w = b2f((ushort)v[3]) - lse;
      o1.x = b2f((ushort)v[4]) - lse; o1.y = b2f((ushort)v[5]) - lse;
      o1.z = b2f((ushort)v[6]) - lse; o1.w = b2f((ushort)v[7]) - lse;
      *(float4*)&row[i * 8] = o0;
      *(float4*)&row[i * 8 + 4] = o1;
    }
  }
}

extern "C" void kernel_launch(void* const* d_in, const int* in_sizes, int n_in,
                              void* d_out, int out_size, void* d_ws, size_t ws_size,
                              hipStream_t stream) {
  const int*   tokens    = (const int*)  d_in[0];
  const int*   lengths   = (const int*)  d_in[1];
  const float* hidden0   = (const float*)d_in[2];
  const float* knowledge = (const float*)d_in[3];
  const float* src_mem   = (const float*)d_in[4];
  const int*   src_len   = (const int*)  d_in[5];
  const float* cue_mem   = (const float*)d_in[6];
  const int*   cue_len   = (const int*)  d_in[7];
  const float* emb       = (const float*)d_in[8];
  const float* w_ih      = (const float*)d_in[9];
  const float* w_hh      = (const float*)d_in[10];
  const float* b_ih      = (const float*)d_in[11];
  const float* b_hh      = (const float*)d_in[12];
  const float* src_wq    = (const float*)d_in[13];
  const float* src_bq    = (const float*)d_in[14];
  const float* src_wm    = (const float*)d_in[15];
  const float* src_v     = (const float*)d_in[16];
  const float* cue_wq    = (const float*)d_in[17];
  const float* cue_bq    = (const float*)d_in[18];
  const float* cue_wm    = (const float*)d_in[19];
  const float* cue_v     = (const float*)d_in[20];
  const float* w_out1    = (const float*)d_in[21];
  const float* b_out1    = (const float*)d_in[22];
  const float* w_out2    = (const float*)d_in[23];
  const float* b_out2    = (const float*)d_in[24];

  float* out_lp = (float*)d_out;                    // (B,T,V)
  float* out_hm = out_lp + (size_t)M_ * V_;         // (B,T,H)
  float* out_hf = out_hm + (size_t)M_ * H_;         // (B,H)

  // ---- scratch carved out of the (not-yet-written) logits region of d_out ----
  char* scb = (char*)d_out;
  size_t off = 0;
  auto alloc = [&](size_t bytes) -> void* {
    void* p = scb + off;
    off = (off + bytes + 255) & ~(size_t)255;
    return p;
  };
  float*  GI    = (float*) alloc((size_t)M_ * G3_ * 4);
  float*  QXKs  = (float*) alloc((size_t)M_ * A_ * 4);
  float*  QXKc  = (float*) alloc((size_t)M_ * A_ * 4);
  float*  QHs   = (float*) alloc((size_t)M_ * A_ * 4);
  float*  QHc   = (float*) alloc((size_t)M_ * A_ * 4);
  float*  CTXs  = (float*) alloc((size_t)M_ * H_ * 4);
  float*  CTXc  = (float*) alloc((size_t)M_ * H_ * 4);
  ushort* OUTIN = (ushort*)alloc((size_t)M_ * OUTIN_ * 2);
  ushort* XBF   = (ushort*)alloc((size_t)M_ * E_ * 2);
  ushort* WIHT  = (ushort*)alloc((size_t)G3_ * E_ * 2);
  ushort* WQXTs = (ushort*)alloc((size_t)A_ * E_ * 2);
  ushort* WQXTc = (ushort*)alloc((size_t)A_ * E_ * 2);
  ushort* WQHTs = (ushort*)alloc((size_t)A_ * H_ * 2);
  ushort* WQHTc = (ushort*)alloc((size_t)A_ * H_ * 2);
  ushort* WMTs  = (ushort*)alloc((size_t)A_ * H_ * 2);
  ushort* WMTc  = (ushort*)alloc((size_t)A_ * H_ * 2);
  ushort* WO1T  = (ushort*)alloc((size_t)H_ * OUTIN_ * 2);
  ushort* MEMBs = (ushort*)alloc((size_t)B_ * S_ * H_ * 2);
  ushort* MEMBc = (ushort*)alloc((size_t)B_ * S_ * H_ * 2);
  float*  MKs   = (float*) alloc((size_t)B_ * S_ * A_ * 4);
  float*  MKc   = (float*) alloc((size_t)B_ * S_ * A_ * 4);
  float*  KQs   = (float*) alloc((size_t)B_ * A_ * 4);
  float*  KQc   = (float*) alloc((size_t)B_ * A_ * 4);
  ushort* HPB   = (ushort*)alloc((size_t)(T_ + 1) * B_ * H_ * 2);  // bf16 h slabs

  // ---- d_ws: padded barrier flags + what must survive into the logits GEMM ----
  uint* FLAGS = (uint*)d_ws;                                          // 64 x 128B slots
  ushort* WO2T = (ushort*)((char*)d_ws + 8192);                       // (V x H) bf16
  ushort* HID1 = (ushort*)((char*)d_ws + 8192 + (size_t)V_ * H_ * 2); // (M x H) bf16

  dim3 blk(256);
  hipMemsetAsync(FLAGS, 0, 8192, stream);

  // prologue needed BEFORE the fused kernel: scan inputs + worker-job inputs
  transpose_k<<<dim3(G3_ / 64, E_ / 64), blk, 0, stream>>>(w_ih, WIHT, E_, G3_);
  transpose_k<<<dim3(A_ / 64, E_ / 64), blk, 0, stream>>>(src_wq, WQXTs, E_, A_);
  transpose_k<<<dim3(A_ / 64, H_ / 64), blk, 0, stream>>>(src_wq + (size_t)E_ * A_, WQHTs, H_, A_);
  transpose_k<<<dim3(A_ / 64, E_ / 64), blk, 0, stream>>>(cue_wq, WQXTc, E_, A_);
  transpose_k<<<dim3(A_ / 64, H_ / 64), blk, 0, stream>>>(cue_wq + (size_t)E_ * A_, WQHTc, H_, A_);
  transpose_k<<<dim3(A_ / 64, H_ / 64), blk, 0, stream>>>(src_wm, WMTs, H_, A_);
  transpose_k<<<dim3(A_ / 64, H_ / 64), blk, 0, stream>>>(cue_wm, WMTc, H_, A_);
  convert_k<<<(B_ * S_ * H_ + 255) / 256, blk, 0, stream>>>(src_mem, MEMBs, B_ * S_ * H_);
  convert_k<<<(B_ * S_ * H_ + 255) / 256, blk, 0, stream>>>(cue_mem, MEMBc, B_ * S_ * H_);
  gather_k<<<M_, blk, 0, stream>>>(tokens, emb, XBF);

  // GI GEMM (scan input)
  gemm_bt<0, 0, 1><<<dim3(G3_ / 128, M_ / 128), blk, 0, stream>>>(XBF, WIHT, b_ih, GI, M_, G3_, E_);
  inith_k<<<(B_ * H_) / 256, blk, 0, stream>>>(hidden0, HPB);

  // fused: scan (32 blocks) + dependency-free prologue jobs (224 worker blocks)
  FArgs P;
  P.w_hh = w_hh; P.b_hh = b_hh; P.gi = GI; P.h0 = hidden0;
  P.lengths = lengths; P.hpb = HPB; P.hidmem = out_hm; P.hfinal = out_hf; P.flags = FLAGS;
  P.w_out1 = w_out1; P.w_out2 = w_out2; P.knowledge = knowledge;
  P.src_wq = src_wq; P.src_bq = src_bq; P.cue_wq = cue_wq; P.cue_bq = cue_bq;
  P.wo1t = WO1T; P.wo2t = WO2T; P.kqs = KQs; P.kqc = KQc;
  P.xbf = XBF; P.wqxts = WQXTs; P.wqxtc = WQXTc;
  P.membs = MEMBs; P.membc = MEMBc; P.wmts = WMTs; P.wmtc = WMTc;
  P.qxks = QXKs; P.qxkc = QXKc; P.mks = MKs; P.mkc = MKc;
  scanfused_k<<<dim3(256), blk, 0, stream>>>(P);

  // parallel attention over all (b,t)
  gemm_bt<0, 0, 0><<<dim3(A_ / 128, M_ / 128), blk, 0, stream>>>(HPB, WQHTs, nullptr, QHs, M_, A_, H_);
  gemm_bt<0, 0, 0><<<dim3(A_ / 128, M_ / 128), blk, 0, stream>>>(HPB, WQHTc, nullptr, QHc, M_, A_, H_);
  attn_k<<<M_, blk, 0, stream>>>(QXKs, QHs, KQs, MKs, MEMBs, src_v, src_len, CTXs);
  attn_k<<<M_, blk, 0, stream>>>(QXKc, QHc, KQc, MKc, MEMBc, cue_v, cue_len, CTXc);

  // output head: logits as bf16 into the f32 row slots, then fused LSE+subtract
  assemble_k<<<M_, blk, 0, stream>>>(XBF, out_hm, knowledge, CTXs, CTXc, lengths, OUTIN);
  gemm_bt<1, 0, 1><<<dim3(H_ / 128, M_ / 128), blk, 0, stream>>>(OUTIN, WO1T, b_out1, HID1, M_, H_, OUTIN_);
  gemm_bt<2, 1, 1><<<dim3(V_ / 128, M_ / 128), blk, 0, stream>>>(HID1, WO2T, b_out2, out_lp, M_, V_, H_);
  logsoftmax_k<<<M_, blk, 0, stream>>>(out_lp);
}

// Round 15
// 1311.730 us; speedup vs baseline: 1.1719x; 1.0673x over previous
//
#include <hip/hip_runtime.h>

typedef unsigned int uint;
typedef unsigned short ushort;
using short8 = __attribute__((ext_vector_type(8))) short;
using f32x4  = __attribute__((ext_vector_type(4))) float;

#define DEVFN __device__ __forceinline__

constexpr int B_ = 32, T_ = 128, E_ = 256, H_ = 512, A_ = 256, V_ = 32000, S_ = 64;
constexpr int G3_ = 3 * H_;          // 1536
constexpr int OUTIN_ = E_ + 4 * H_;  // 2304
constexpr int M_ = B_ * T_;          // 4096 rows, convention row = t*32 + b

DEVFN ushort f2b(float f) {  // f32 -> bf16 RNE
  uint u = __float_as_uint(f);
  u += 0x7fffu + ((u >> 16) & 1u);
  return (ushort)(u >> 16);
}
DEVFN float b2f(ushort b) { return __uint_as_float(((uint)b) << 16); }
DEVFN float sigmoid_f(float x) { return 1.f / (1.f + __expf(-x)); }
DEVFN float tanh_f(float x) { float e = __expf(2.f * x); return 1.f - 2.f / (e + 1.f); }
DEVFN f32x4 MFMA16(short8 a, short8 b, f32x4 c) {
  return __builtin_amdgcn_mfma_f32_16x16x32_bf16(a, b, c, 0, 0, 0);
}

// ---- 64x64 transpose tile job: in f32 (R x C) -> out bf16 (C x R) ----
DEVFN void trans_tile(const float* in, ushort* out, int R, int C, int bx, int by,
                      int tid, char* smem) {
  ushort (*tile)[65] = (ushort(*)[65])smem;
  int c0 = bx * 64, r0 = by * 64;
  int tx = tid & 63, ty = tid >> 6;
#pragma unroll
  for (int k = 0; k < 16; k++) {
    int i = ty + k * 4;
    int r = r0 + i, c = c0 + tx;
    if (r < R && c < C) tile[tx][i] = f2b(in[(size_t)r * C + c]);
  }
  __syncthreads();
#pragma unroll
  for (int k = 0; k < 16; k++) {
    int j = ty + k * 4;
    int c = c0 + j, r = r0 + tx;
    if (r < R && c < C) out[(size_t)c * R + r] = tile[j][tx];
  }
  __syncthreads();  // smem reuse safety
}

// ================= fused independent prologue: transposes+converts+gather+inith =================
struct PArgs {
  const float *w_ih, *src_wq, *cue_wq, *src_wm, *cue_wm, *src_mem, *cue_mem, *h0, *emb;
  const int* tokens;
  ushort *wiht, *wqxts, *wqxtc, *wqht2, *wmts, *wmtc, *membs, *membc, *hpb, *xbf;
};

__global__ __launch_bounds__(256) void prologue_k(PArgs P) {
  __shared__ __align__(16) char smem[8448];
  const int j = blockIdx.x, tid = threadIdx.x;
  if (j < 96) {
    trans_tile(P.w_ih, P.wiht, E_, G3_, j % 24, j / 24, tid, smem);
  } else if (j < 112) {
    int q = j - 96;  trans_tile(P.src_wq, P.wqxts, E_, A_, q & 3, q >> 2, tid, smem);
  } else if (j < 144) {
    int q = j - 112; trans_tile(P.src_wq + (size_t)E_ * A_, P.wqht2, H_, A_, q & 3, q >> 2, tid, smem);
  } else if (j < 160) {
    int q = j - 144; trans_tile(P.cue_wq, P.wqxtc, E_, A_, q & 3, q >> 2, tid, smem);
  } else if (j < 192) {
    int q = j - 160; trans_tile(P.cue_wq + (size_t)E_ * A_, P.wqht2 + (size_t)256 * H_, H_, A_, q & 3, q >> 2, tid, smem);
  } else if (j < 224) {
    int q = j - 192; trans_tile(P.src_wm, P.wmts, H_, A_, q & 3, q >> 2, tid, smem);
  } else if (j < 256) {
    int q = j - 224; trans_tile(P.cue_wm, P.wmtc, H_, A_, q & 3, q >> 2, tid, smem);
  } else if (j < 512) {
    int base = (j - 256) * 4096;
#pragma unroll
    for (int i = 0; i < 16; i++) { int g = base + i * 256 + tid; P.membs[g] = f2b(P.src_mem[g]); }
  } else if (j < 768) {
    int base = (j - 512) * 4096;
#pragma unroll
    for (int i = 0; i < 16; i++) { int g = base + i * 256 + tid; P.membc[g] = f2b(P.cue_mem[g]); }
  } else if (j < 832) {
    int g = (j - 768) * 256 + tid;
    P.hpb[g] = f2b(P.h0[g]);
  } else {
    int r = j - 832;  // 4096 rows, r = t*32+b
    int t = r >> 5, b = r & 31;
    int tok = P.tokens[b * T_ + t];
    P.xbf[(size_t)r * E_ + tid] = f2b(P.emb[(size_t)tok * E_ + tid]);
  }
}
constexpr int NPRO = 4928;

// ---------------- generic bf16 MFMA GEMM (r9-proven staging + XCD swizzle) ----------------
// OUTBF: 0 = f32 out, 1 = bf16 out (packed N stride), 2 = bf16 into f32-row slots (stride 2N)
template <int OUTBF, int PERM, int HASBIAS>
__global__ __launch_bounds__(256) void gemm_bt(const ushort* __restrict__ Ag,
                                               const ushort* __restrict__ Btg,
                                               const float* __restrict__ bias,
                                               void* __restrict__ Cg, int M, int N, int K) {
  __shared__ __align__(16) ushort Ash[128][40];
  __shared__ __align__(16) ushort Bsh[128][40];
  const int nbx = gridDim.x;
  const int nwg = nbx * gridDim.y;
  const int lin = blockIdx.y * nbx + blockIdx.x;
  const int cpx = nwg >> 3;
  const int swz = (lin & 7) * cpx + (lin >> 3);
  const int m0 = (swz / nbx) * 128, n0 = (swz % nbx) * 128;
  const int tid = threadIdx.x;
  const int wave = tid >> 6, lane = tid & 63, lr = lane & 15, lg = lane >> 4;
  const int wr = wave >> 1, wc = wave & 1;
  f32x4 acc[4][4] = {};
  for (int kk = 0; kk < K; kk += 32) {
    {
      int r = tid >> 2, q = tid & 3;
      *(short8*)&Ash[r][q * 8] = *(const short8*)&Ag[(size_t)(m0 + r) * K + kk + q * 8];
      *(short8*)&Bsh[r][q * 8] = *(const short8*)&Btg[(size_t)(n0 + r) * K + kk + q * 8];
      r += 64;
      *(short8*)&Ash[r][q * 8] = *(const short8*)&Ag[(size_t)(m0 + r) * K + kk + q * 8];
      *(short8*)&Bsh[r][q * 8] = *(const short8*)&Btg[(size_t)(n0 + r) * K + kk + q * 8];
    }
    __syncthreads();
    short8 af[4], bfr[4];
#pragma unroll
    for (int mi = 0; mi < 4; mi++) af[mi] = *(const short8*)&Ash[wr * 64 + mi * 16 + lr][lg * 8];
#pragma unroll
    for (int ni = 0; ni < 4; ni++) bfr[ni] = *(const short8*)&Bsh[wc * 64 + ni * 16 + lr][lg * 8];
#pragma unroll
    for (int mi = 0; mi < 4; mi++)
#pragma unroll
      for (int ni = 0; ni < 4; ni++)
        acc[mi][ni] = MFMA16(af[mi], bfr[ni], acc[mi][ni]);
    __syncthreads();
  }
#pragma unroll
  for (int mi = 0; mi < 4; mi++)
#pragma unroll
    for (int ni = 0; ni < 4; ni++) {
      int col = n0 + wc * 64 + ni * 16 + lr;
      float bv = HASBIAS ? bias[col] : 0.f;
#pragma unroll
      for (int r = 0; r < 4; r++) {
        int row = m0 + wr * 64 + mi * 16 + lg * 4 + r;
        int orow = PERM ? ((row & 31) << 7) + (row >> 5) : row;  // t*32+b -> b*128+t
        float v = acc[mi][ni][r] + bv;
        if (OUTBF == 1)      ((ushort*)Cg)[(size_t)orow * N + col] = f2b(v);
        else if (OUTBF == 2) ((ushort*)Cg)[(size_t)orow * 2 * N + col] = f2b(v);
        else                 ((float*)Cg)[(size_t)orow * N + col] = v;
      }
    }
}

// ================= fused scan + independent-prologue-work kernel (r14-proven) =================
struct FArgs {
  // scan
  const float *w_hh, *b_hh, *gi, *h0;
  const int* lengths;
  ushort* hpb;
  float *hidmem, *hfinal;
  uint* flags;
  // workers
  const float *w_out1, *w_out2, *knowledge, *src_wq, *src_bq, *cue_wq, *cue_bq;
  ushort *wo1t, *wo2t;
  float *kqs, *kqc;
  const ushort *xbf, *wqxts, *wqxtc, *membs, *membc, *wmts, *wmtc;
  float *qxks, *qxkc, *mks, *mkc;
};

DEVFN void scan_body(const FArgs& P, int wg, int tid, char* smem) {
  ushort (*pk)[16][16] = (ushort(*)[16][16])smem;
  const int c0 = wg * 16;
  const int wave = tid >> 6, lane = tid & 63, lr = lane & 15, lg = lane >> 4;
  const int c = c0 + lr;

  short8 wf0[16], wf1[16], wf2[16];
#pragma unroll
  for (int kk = 0; kk < 16; kk++) {
    short8 v0, v1, v2;
#pragma unroll
    for (int i = 0; i < 8; i++) {
      int k = kk * 32 + lg * 8 + i;
      v0[i] = (short)f2b(P.w_hh[(size_t)k * G3_ + 0 * H_ + c]);
      v1[i] = (short)f2b(P.w_hh[(size_t)k * G3_ + 1 * H_ + c]);
      v2[i] = (short)f2b(P.w_hh[(size_t)k * G3_ + 2 * H_ + c]);
    }
    wf0[kk] = v0; wf1[kk] = v1; wf2[kk] = v2;
  }
  const float bh0 = P.b_hh[c], bh1 = P.b_hh[H_ + c], bh2 = P.b_hh[2 * H_ + c];
  int len[4];
  float hp[4];
#pragma unroll
  for (int r = 0; r < 4; r++) {
    int bt = 16 * wave + lg * 4 + r;
    len[r] = P.lengths[bt];
    hp[r] = P.h0[(size_t)bt * H_ + c];
  }
  const uint fidx = ((uint)(lane & 31) * 2 + (uint)wave) * 32;

#pragma unroll 1
  for (int t = 0; t < T_; t++) {
    float g0[4], g1[4], g2[4];
#pragma unroll
    for (int r = 0; r < 4; r++) {
      int bt = 16 * wave + lg * 4 + r;
      const float* gr = P.gi + (size_t)(t * 32 + bt) * G3_ + c;
      g0[r] = gr[0]; g1[r] = gr[H_]; g2[r] = gr[2 * H_];
    }
    if (t > 0) {
      while (true) {
        uint f = __hip_atomic_load(&P.flags[fidx], __ATOMIC_RELAXED, __HIP_MEMORY_SCOPE_AGENT);
        if (__all((int)(f >= (uint)t))) break;
        __builtin_amdgcn_s_sleep(1);
      }
    }
    asm volatile("" ::: "memory");

    const ushort* Sb = P.hpb + (size_t)t * (B_ * H_);
    const int rowA = 16 * wave + lr;
    f32x4 a0 = {}, a1 = {}, a2 = {};
#pragma unroll
    for (int kk = 0; kk < 16; kk++) {
      short8 av = *(const short8*)(Sb + rowA * H_ + kk * 32 + lg * 8);
      a0 = MFMA16(av, wf0[kk], a0);
      a1 = MFMA16(av, wf1[kk], a1);
      a2 = MFMA16(av, wf2[kk], a2);
    }

    ushort* Un16 = P.hpb + (size_t)(t + 1) * (B_ * H_);
    float hmv[4];
#pragma unroll
    for (int r = 0; r < 4; r++) {
      float rr = sigmoid_f(g0[r] + a0[r] + bh0);
      float zz = sigmoid_f(g1[r] + a1[r] + bh1);
      float nn = tanh_f(g2[r] + rr * (a2[r] + bh2));
      float hv = (1.f - zz) * nn + zz * hp[r];
      bool valid = t < len[r];
      float hx = valid ? hv : hp[r];
      hp[r] = hx;
      hmv[r] = valid ? hv : 0.f;
      pk[wave][lg * 4 + r][lr] = f2b(hx);
    }
    if (lane < 32) {
      int row = lane >> 1, half = lane & 1;
      short8 v = *(const short8*)&pk[wave][row][half * 8];
      ushort* gp = Un16 + ((size_t)(16 * wave + row) * H_ + c0 + half * 8);
      asm volatile("global_store_dwordx4 %0, %1, off sc1" :: "v"(gp), "v"(v) : "memory");
    }
    asm volatile("s_waitcnt vmcnt(0)" ::: "memory");
    if (lane == 0)
      __hip_atomic_store(&P.flags[(wg * 2 + wave) * 32], (uint)(t + 1),
                         __ATOMIC_RELAXED, __HIP_MEMORY_SCOPE_AGENT);
#pragma unroll
    for (int r = 0; r < 4; r++) {
      int bt = 16 * wave + lg * 4 + r;
      P.hidmem[((size_t)bt * T_ + t) * H_ + c] = hmv[r];
    }
  }
#pragma unroll
  for (int r = 0; r < 4; r++) {
    int bt = 16 * wave + lg * 4 + r;
    P.hfinal[(size_t)bt * H_ + c] = hp[r];
  }
}

DEVFN void kq_job(const float* knowledge, const float* wq, const float* bq,
                  float* kq, int b, int tid) {
  const float* kn = knowledge + b * H_;
  float s = 0.f;
  for (int h = 0; h < H_; h++) s += kn[h] * wq[(size_t)(E_ + H_ + h) * A_ + tid];
  kq[b * A_ + tid] = s + bq[tid];
}

DEVFN void gemm_tile(const ushort* Ag, const ushort* Btg, float* Cg,
                     int N, int K, int m0, int n0, int tid, char* smem) {
  ushort (*Ash)[40] = (ushort(*)[40])smem;
  ushort (*Bsh)[40] = (ushort(*)[40])(smem + 10240);
  const int wave = tid >> 6, lane = tid & 63, lr = lane & 15, lg = lane >> 4;
  const int wr = wave >> 1, wc = wave & 1;
  f32x4 acc[4][4] = {};
  for (int kk = 0; kk < K; kk += 32) {
    {
      int r = tid >> 2, q = tid & 3;
      *(short8*)&Ash[r][q * 8] = *(const short8*)&Ag[(size_t)(m0 + r) * K + kk + q * 8];
      *(short8*)&Bsh[r][q * 8] = *(const short8*)&Btg[(size_t)(n0 + r) * K + kk + q * 8];
      r += 64;
      *(short8*)&Ash[r][q * 8] = *(const short8*)&Ag[(size_t)(m0 + r) * K + kk + q * 8];
      *(short8*)&Bsh[r][q * 8] = *(const short8*)&Btg[(size_t)(n0 + r) * K + kk + q * 8];
    }
    __syncthreads();
    short8 af[4], bfr[4];
#pragma unroll
    for (int mi = 0; mi < 4; mi++) af[mi] = *(const short8*)&Ash[wr * 64 + mi * 16 + lr][lg * 8];
#pragma unroll
    for (int ni = 0; ni < 4; ni++) bfr[ni] = *(const short8*)&Bsh[wc * 64 + ni * 16 + lr][lg * 8];
#pragma unroll
    for (int mi = 0; mi < 4; mi++)
#pragma unroll
      for (int ni = 0; ni < 4; ni++)
        acc[mi][ni] = MFMA16(af[mi], bfr[ni], acc[mi][ni]);
    __syncthreads();
  }
#pragma unroll
  for (int mi = 0; mi < 4; mi++)
#pragma unroll
    for (int ni = 0; ni < 4; ni++) {
      int col = n0 + wc * 64 + ni * 16 + lr;
#pragma unroll
      for (int r = 0; r < 4; r++) {
        int row = m0 + wr * 64 + mi * 16 + lg * 4 + r;
        Cg[(size_t)row * N + col] = acc[mi][ni][r];
      }
    }
}

constexpr int NJOB = 288 + 4000 + 64 + 128 + 64;  // 4544

__global__ __launch_bounds__(256, 1) void scanfused_k(FArgs P) {
  __shared__ __align__(16) char smem[20480];
  const int bid = blockIdx.x, tid = threadIdx.x;
  if (bid < 32) {
    if (tid < 128) scan_body(P, bid, tid, smem);
    return;
  }
  for (int j = bid - 32; j < NJOB; j += 224) {
    if (j < 288) {
      trans_tile(P.w_out1, P.wo1t, OUTIN_, H_, j & 7, j >> 3, tid, smem);
    } else if (j < 4288) {
      int q = j - 288;
      trans_tile(P.w_out2, P.wo2t, H_, V_, q % 500, q / 500, tid, smem);
    } else if (j < 4352) {
      int q = j - 4288;
      if (q < 32) kq_job(P.knowledge, P.src_wq, P.src_bq, P.kqs, q, tid);
      else        kq_job(P.knowledge, P.cue_wq, P.cue_bq, P.kqc, q - 32, tid);
    } else if (j < 4480) {
      int q = j - 4352;
      int mat = q >> 6; q &= 63;
      gemm_tile(P.xbf, mat ? P.wqxtc : P.wqxts, mat ? P.qxkc : P.qxks,
                A_, E_, (q >> 1) * 128, (q & 1) * 128, tid, smem);
    } else {
      int q = j - 4480;
      int mat = q >> 5; q &= 31;
      gemm_tile(mat ? P.membc : P.membs, mat ? P.wmtc : P.wmts, mat ? P.mkc : P.mks,
                A_, H_, (q >> 1) * 128, (q & 1) * 128, tid, smem);
    }
  }
}

// ---------------- combined MLP attention (both mats), one block per (mat,b,t) ----------------
struct AArgs {
  const float* qxk[2];
  const float* kq[2];
  const float* mk[2];
  const ushort* memb[2];
  const float* vvec[2];
  const int* slen[2];
  float* ctx[2];
  const float* qh2;  // (M x 512), cols [mat*256, mat*256+256)
};

__global__ __launch_bounds__(256) void attn2_k(AArgs P) {
  __shared__ float qf[A_], vv[A_], sc[S_];
  int bid = blockIdx.x;             // 0..8191
  int mat = bid >> 12;
  int bx = bid & 4095;              // b*T + t
  int b = bx >> 7, t = bx & 127;
  int row = t * B_ + b;
  int tid = threadIdx.x;
  qf[tid] = P.qxk[mat][(size_t)row * A_ + tid] +
            P.qh2[(size_t)row * 512 + mat * 256 + tid] + P.kq[mat][b * A_ + tid];
  vv[tid] = P.vvec[mat][tid];
  __syncthreads();
  int s = tid >> 2, q4 = tid & 3;
  const float* mkr = P.mk[mat] + ((size_t)(b * S_) + s) * A_;
  float part = 0.f;
#pragma unroll 4
  for (int i = 0; i < 64; i++) {
    int a = q4 + (i << 2);  // quad-interleaved -> coalesced 16B per quad
    part += tanh_f(qf[a] + mkr[a]) * vv[a];
  }
  part += __shfl_xor(part, 1, 64);
  part += __shfl_xor(part, 2, 64);
  if (q4 == 0) sc[s] = part;
  __syncthreads();
  if (tid < S_) {
    float v = (tid < P.slen[mat][b]) ? sc[tid] : -1e9f;
    float mm = v;
    for (int off = 1; off < 64; off <<= 1) mm = fmaxf(mm, __shfl_xor(mm, off, 64));
    float e = __expf(v - mm);
    float ss = e;
    for (int off = 1; off < 64; off <<= 1) ss += __shfl_xor(ss, off, 64);
    sc[tid] = e / ss;
  }
  __syncthreads();
  float c0 = 0.f, c1 = 0.f;
  const ushort* mb = P.memb[mat] + (size_t)b * S_ * H_;
  for (int ss2 = 0; ss2 < S_; ss2++) {
    float w = sc[ss2];
    c0 += w * b2f(mb[ss2 * H_ + tid]);
    c1 += w * b2f(mb[ss2 * H_ + tid + 256]);
  }
  P.ctx[mat][(size_t)row * H_ + tid] = c0;
  P.ctx[mat][(size_t)row * H_ + tid + 256] = c1;
}

// ---------------- assemble out_in (bf16, masked); h_new taken from hidmem ----------------
__global__ __launch_bounds__(256) void assemble_k(
    const ushort* __restrict__ xbf, const float* __restrict__ hm,
    const float* __restrict__ knowledge, const float* __restrict__ ctxs,
    const float* __restrict__ ctxc, const int* __restrict__ lengths,
    ushort* __restrict__ outin) {
  int r = blockIdx.x;
  int t = r >> 5, b = r & 31;
  bool valid = t < lengths[b];
  int tid = threadIdx.x;
  ushort* dst = outin + (size_t)r * OUTIN_;
#pragma unroll
  for (int kblk = 0; kblk < 9; kblk++) {
    int i = kblk * 256 + tid;
    ushort v;
    if (i < E_)               v = xbf[(size_t)r * E_ + i];
    else if (i < E_ + H_)     v = f2b(hm[((size_t)b * T_ + t) * H_ + i - E_]);
    else if (i < E_ + 2 * H_) v = f2b(knowledge[b * H_ + i - (E_ + H_)]);
    else if (i < E_ + 3 * H_) v = f2b(ctxs[(size_t)r * H_ + i - (E_ + 2 * H_)]);
    else                      v = f2b(ctxc[(size_t)r * H_ + i - (E_ + 3 * H_)]);
    dst[i] = valid ? v : (ushort)0;
  }
}

// ---------------- row log_softmax: bf16 logits (first half of f32 row slot) -> f32 out ----------------
__global__ __launch_bounds__(256) void logsoftmax_k(float* __restrict__ logits) {
  __shared__ float redm[4], reds[4];
  float* row = logits + (size_t)blockIdx.x * V_;
  const short8* rg = (const short8*)row;  // bf16 payload occupies first V_*2 bytes
  const int tid = threadIdx.x;
  short8 buf[16];
  float m = -3.4e38f, s = 0.f;
#pragma unroll
  for (int k = 0; k < 16; k++) {
    int i = tid + k * 256;
    if (i < V_ / 8) {
      short8 v = rg[i];
      buf[k] = v;
      float f0 = b2f((ushort)v[0]), f1 = b2f((ushort)v[1]);
      float f2 = b2f((ushort)v[2]), f3 = b2f((ushort)v[3]);
      float f4 = b2f((ushort)v[4]), f5 = b2f((ushort)v[5]);
      float f6 = b2f((ushort)v[6]), f7 = b2f((ushort)v[7]);
      float vm = fmaxf(fmaxf(fmaxf(f0, f1), fmaxf(f2, f3)),
                       fmaxf(fmaxf(f4, f5), fmaxf(f6, f7)));
      float nm = fmaxf(m, vm);
      s = s * __expf(m - nm) + __expf(f0 - nm) + __expf(f1 - nm) + __expf(f2 - nm) +
          __expf(f3 - nm) + __expf(f4 - nm) + __expf(f5 - nm) + __expf(f6 - nm) +
          __expf(f7 - nm);
      m = nm;
    }
  }
  for (int off = 1; off < 64; off <<= 1) {
    float om = __shfl_xor(m, off, 64), os = __shfl_xor(s, off, 64);
    float nm = fmaxf(m, om);
    s = s * __expf(m - nm) + os * __expf(om - nm);
    m = nm;
  }
  if ((tid & 63) == 0) { redm[tid >> 6] = m; reds[tid >> 6] = s; }
  __syncthreads();
  float M = fmaxf(fmaxf(redm[0], redm[1]), fmaxf(redm[2], redm[3]));
  float S = reds[0] * __expf(redm[0] - M) + reds[1] * __expf(redm[1] - M) +
            reds[2] * __expf(redm[2] - M) + reds[3] * __expf(redm[3] - M);
  float lse = M + __logf(S);
  __syncthreads();  // all reads of bf16 payload complete before f32 overwrite
#pragma unroll
  for (int k = 0; k < 16; k++) {
    int i = tid + k * 256;
    if (i < V_ / 8) {
      short8 v = buf[k];
      float4 o0, o1;
      o0.x = b2f((ushort)v[0]) - lse; o0.y = b2f((ushort)v[1]) - lse;
      o0.z = b2f((ushort)v[2]) - lse; o0.w = b2f((ushort)v[3]) - lse;
      o1.x = b2f((ushort)v[4]) - lse; o1.y = b2f((ushort)v[5]) - lse;
      o1.z = b2f((ushort)v[6]) - lse; o1.w = b2f((ushort)v[7]) - lse;
      *(float4*)&row[i * 8] = o0;
      *(float4*)&row[i * 8 + 4] = o1;
    }
  }
}

extern "C" void kernel_launch(void* const* d_in, const int* in_sizes, int n_in,
                              void* d_out, int out_size, void* d_ws, size_t ws_size,
                              hipStream_t stream) {
  const int*   tokens    = (const int*)  d_in[0];
  const int*   lengths   = (const int*)  d_in[1];
  const float* hidden0   = (const float*)d_in[2];
  const float* knowledge = (const float*)d_in[3];
  const float* src_mem   = (const float*)d_in[4];
  const int*   src_len   = (const int*)  d_in[5];
  const float* cue_mem   = (const float*)d_in[6];
  const int*   cue_len   = (const int*)  d_in[7];
  const float* emb       = (const float*)d_in[8];
  const float* w_ih      = (const float*)d_in[9];
  const float* w_hh      = (const float*)d_in[10];
  const float* b_ih      = (const float*)d_in[11];
  const float* b_hh      = (const float*)d_in[12];
  const float* src_wq    = (const float*)d_in[13];
  const float* src_bq    = (const float*)d_in[14];
  const float* src_wm    = (const float*)d_in[15];
  const float* src_v     = (const float*)d_in[16];
  const float* cue_wq    = (const float*)d_in[17];
  const float* cue_bq    = (const float*)d_in[18];
  const float* cue_wm    = (const float*)d_in[19];
  const float* cue_v     = (const float*)d_in[20];
  const float* w_out1    = (const float*)d_in[21];
  const float* b_out1    = (const float*)d_in[22];
  const float* w_out2    = (const float*)d_in[23];
  const float* b_out2    = (const float*)d_in[24];

  float* out_lp = (float*)d_out;                    // (B,T,V)
  float* out_hm = out_lp + (size_t)M_ * V_;         // (B,T,H)
  float* out_hf = out_hm + (size_t)M_ * H_;         // (B,H)

  // ---- scratch carved out of the (not-yet-written) logits region of d_out ----
  char* scb = (char*)d_out;
  size_t off = 0;
  auto alloc = [&](size_t bytes) -> void* {
    void* p = scb + off;
    off = (off + bytes + 255) & ~(size_t)255;
    return p;
  };
  float*  GI    = (float*) alloc((size_t)M_ * G3_ * 4);
  float*  QXKs  = (float*) alloc((size_t)M_ * A_ * 4);
  float*  QXKc  = (float*) alloc((size_t)M_ * A_ * 4);
  float*  QH2   = (float*) alloc((size_t)M_ * 512 * 4);
  float*  CTXs  = (float*) alloc((size_t)M_ * H_ * 4);
  float*  CTXc  = (float*) alloc((size_t)M_ * H_ * 4);
  ushort* OUTIN = (ushort*)alloc((size_t)M_ * OUTIN_ * 2);
  ushort* XBF   = (ushort*)alloc((size_t)M_ * E_ * 2);
  ushort* WIHT  = (ushort*)alloc((size_t)G3_ * E_ * 2);
  ushort* WQXTs = (ushort*)alloc((size_t)A_ * E_ * 2);
  ushort* WQXTc = (ushort*)alloc((size_t)A_ * E_ * 2);
  ushort* WQHT2 = (ushort*)alloc((size_t)512 * H_ * 2);
  ushort* WMTs  = (ushort*)alloc((size_t)A_ * H_ * 2);
  ushort* WMTc  = (ushort*)alloc((size_t)A_ * H_ * 2);
  ushort* WO1T  = (ushort*)alloc((size_t)H_ * OUTIN_ * 2);
  ushort* MEMBs = (ushort*)alloc((size_t)B_ * S_ * H_ * 2);
  ushort* MEMBc = (ushort*)alloc((size_t)B_ * S_ * H_ * 2);
  float*  MKs   = (float*) alloc((size_t)B_ * S_ * A_ * 4);
  float*  MKc   = (float*) alloc((size_t)B_ * S_ * A_ * 4);
  float*  KQs   = (float*) alloc((size_t)B_ * A_ * 4);
  float*  KQc   = (float*) alloc((size_t)B_ * A_ * 4);
  ushort* HPB   = (ushort*)alloc((size_t)(T_ + 1) * B_ * H_ * 2);  // bf16 h slabs

  // ---- d_ws: padded barrier flags + what must survive into the logits GEMM ----
  uint* FLAGS = (uint*)d_ws;                                          // 64 x 128B slots
  ushort* WO2T = (ushort*)((char*)d_ws + 8192);                       // (V x H) bf16
  ushort* HID1 = (ushort*)((char*)d_ws + 8192 + (size_t)V_ * H_ * 2); // (M x H) bf16

  dim3 blk(256);
  hipMemsetAsync(FLAGS, 0, 8192, stream);

  // fused independent prologue: all transposes + converts + gather + inith in one launch
  PArgs PP;
  PP.w_ih = w_ih; PP.src_wq = src_wq; PP.cue_wq = cue_wq;
  PP.src_wm = src_wm; PP.cue_wm = cue_wm;
  PP.src_mem = src_mem; PP.cue_mem = cue_mem; PP.h0 = hidden0; PP.emb = emb;
  PP.tokens = tokens;
  PP.wiht = WIHT; PP.wqxts = WQXTs; PP.wqxtc = WQXTc; PP.wqht2 = WQHT2;
  PP.wmts = WMTs; PP.wmtc = WMTc; PP.membs = MEMBs; PP.membc = MEMBc;
  PP.hpb = HPB; PP.xbf = XBF;
  prologue_k<<<dim3(NPRO), blk, 0, stream>>>(PP);

  // GI GEMM (scan input)
  gemm_bt<0, 0, 1><<<dim3(G3_ / 128, M_ / 128), blk, 0, stream>>>(XBF, WIHT, b_ih, GI, M_, G3_, E_);

  // fused: scan (32 blocks) + dependency-free prologue jobs (224 worker blocks)
  FArgs P;
  P.w_hh = w_hh; P.b_hh = b_hh; P.gi = GI; P.h0 = hidden0;
  P.lengths = lengths; P.hpb = HPB; P.hidmem = out_hm; P.hfinal = out_hf; P.flags = FLAGS;
  P.w_out1 = w_out1; P.w_out2 = w_out2; P.knowledge = knowledge;
  P.src_wq = src_wq; P.src_bq = src_bq; P.cue_wq = cue_wq; P.cue_bq = cue_bq;
  P.wo1t = WO1T; P.wo2t = WO2T; P.kqs = KQs; P.kqc = KQc;
  P.xbf = XBF; P.wqxts = WQXTs; P.wqxtc = WQXTc;
  P.membs = MEMBs; P.membc = MEMBc; P.wmts = WMTs; P.wmtc = WMTc;
  P.qxks = QXKs; P.qxkc = QXKc; P.mks = MKs; P.mkc = MKc;
  scanfused_k<<<dim3(256), blk, 0, stream>>>(P);

  // merged QH GEMM: (M x H) @ WQHT2^T -> (M x 512)
  gemm_bt<0, 0, 0><<<dim3(512 / 128, M_ / 128), blk, 0, stream>>>(HPB, WQHT2, nullptr, QH2, M_, 512, H_);

  // combined attention over both mats and all (b,t)
  AArgs AA;
  AA.qxk[0] = QXKs; AA.qxk[1] = QXKc;
  AA.kq[0] = KQs; AA.kq[1] = KQc;
  AA.mk[0] = MKs; AA.mk[1] = MKc;
  AA.memb[0] = MEMBs; AA.memb[1] = MEMBc;
  AA.vvec[0] = src_v; AA.vvec[1] = cue_v;
  AA.slen[0] = src_len; AA.slen[1] = cue_len;
  AA.ctx[0] = CTXs; AA.ctx[1] = CTXc;
  AA.qh2 = QH2;
  attn2_k<<<dim3(2 * M_), blk, 0, stream>>>(AA);

  // output head: logits as bf16 into the f32 row slots, then fused LSE+subtract
  assemble_k<<<M_, blk, 0, stream>>>(XBF, out_hm, knowledge, CTXs, CTXc, lengths, OUTIN);
  gemm_bt<1, 0, 1><<<dim3(H_ / 128, M_ / 128), blk, 0, stream>>>(OUTIN, WO1T, b_out1, HID1, M_, H_, OUTIN_);
  gemm_bt<2, 1, 1><<<dim3(V_ / 128, M_ / 128), blk, 0, stream>>>(HID1, WO2T, b_out2, out_lp, M_, V_, H_);
  logsoftmax_k<<<M_, blk, 0, stream>>>(out_lp);
}